// Round 10
// baseline (363.466 us; speedup 1.0000x reference)
//
#include <hip/hip_runtime.h>
#include <hip/hip_bf16.h>

#define D_MODEL 1024
#define N_HEADS 16
#define DK      64
#define SEQ     2048
#define BATCH   2
#define D_FF    4096
#define ROWS    (BATCH*SEQ)   // 4096
#define LN_EPS  1e-6f
#define KTILE   128           // fattn K-tile

typedef __hip_bfloat16 bf16;
typedef __attribute__((ext_vector_type(8))) short frag8;   // 8 bf16 (MFMA A/B)
typedef __attribute__((ext_vector_type(4))) float facc4;   // 4 f32 (MFMA C/D)

__device__ inline float bf2f(unsigned short u){ return __uint_as_float(((unsigned)u) << 16); }
__device__ inline float toF(bf16 v){ return __bfloat162float(v); }
__device__ inline unsigned short f2bu(float f){ bf16 h = __float2bfloat16(f); return *reinterpret_cast<unsigned short*>(&h); }

// 2 f32 -> packed 2x bf16 (RNE), single instruction on gfx950.
__device__ inline unsigned cvtpk_bf16(float lo, float hi){
    unsigned r;
    asm("v_cvt_pk_bf16_f32 %0, %1, %2" : "=v"(r) : "v"(lo), "v"(hi));
    return r;
}

__device__ inline float ld1(const void* p, size_t idx, bool f32) {
    return f32 ? ((const float*)p)[idx] : toF(((const bf16*)p)[idx]);
}

struct U8 { unsigned short v[8]; };
__device__ inline U8 ld8bf(const void* p, size_t idx, bool f32) {
    U8 r;
    if (!f32) {
        *reinterpret_cast<uint4*>(r.v) = *reinterpret_cast<const uint4*>((const unsigned short*)p + idx);
    } else {
        const float* f = (const float*)p + idx;
        const float4 a = *reinterpret_cast<const float4*>(f);
        const float4 b = *reinterpret_cast<const float4*>(f + 4);
        r.v[0]=f2bu(a.x); r.v[1]=f2bu(a.y); r.v[2]=f2bu(a.z); r.v[3]=f2bu(a.w);
        r.v[4]=f2bu(b.x); r.v[5]=f2bu(b.y); r.v[6]=f2bu(b.z); r.v[7]=f2bu(b.w);
    }
    return r;
}

// 8 f32 values from alpha/bias-style vectors, dtype-aware, vectorized (G13).
__device__ inline void ld8f(const void* p, int idx, bool f32, float* o) {
    if (!f32) {
        uint4 u = *reinterpret_cast<const uint4*>((const unsigned short*)p + idx);
        const unsigned short* us = reinterpret_cast<const unsigned short*>(&u);
        #pragma unroll
        for (int j = 0; j < 8; ++j) o[j] = bf2f(us[j]);
    } else {
        const float* f = (const float*)p + idx;
        const float4 a = *reinterpret_cast<const float4*>(f);
        const float4 b = *reinterpret_cast<const float4*>(f + 4);
        o[0]=a.x; o[1]=a.y; o[2]=a.z; o[3]=a.w;
        o[4]=b.x; o[5]=b.y; o[6]=b.z; o[7]=b.w;
    }
}

// Async global->LDS, 16B/lane. LDS dst is wave-uniform base; lane i -> dst+i*16B.
__device__ inline void gld16(const void* g, void* l) {
    __builtin_amdgcn_global_load_lds(
        reinterpret_cast<const __attribute__((address_space(1))) void*>(
            reinterpret_cast<uintptr_t>(g)),
        reinterpret_cast<__attribute__((address_space(3))) void*>(
            (unsigned int)reinterpret_cast<uintptr_t>(l)),
        16, 0, 0);
}

// Dtype probe: fp32 bits misread as bf16 give Inf/NaN/huge values.
__global__ void probe_kernel(const void* __restrict__ xp, int* __restrict__ flag) {
    __shared__ int hit;
    if (threadIdx.x == 0) hit = 0;
    __syncthreads();
    const bf16* p = (const bf16*)xp;
    int bad = 0;
    for (int i = threadIdx.x; i < 8192; i += 256) {
        float v = fabsf(toF(p[i]));
        if (!(v <= 1e5f)) bad = 1;
    }
    if (bad) atomicOr(&hit, 1);
    __syncthreads();
    if (threadIdx.x == 0) *flag = hit;   // 1 => inputs are fp32
}

// x (flag dtype) -> canonical bf16 ws buffer. 8 elems/thread.
__global__ __launch_bounds__(256) void xcvt_kernel(const void* __restrict__ x,
    bf16* __restrict__ out, const int* __restrict__ flagp)
{
    const bool f32 = (*flagp) != 0;
    const size_t i = ((size_t)blockIdx.x * 256 + threadIdx.x) * 8;
    U8 d = ld8bf(x, i, f32);
    *reinterpret_cast<uint4*>(out + i) = *reinterpret_cast<const uint4*>(d.v);
}

// Shared 64x64 transpose tile body: W[k0+.., n0+..] -> WT[n0+..][k0+..].
__device__ inline void ttile(const void* W, bf16* WT, int K, int N,
                             int n0, int k0, bool f32, float (*tile)[65], int t)
{
    const int lr = t >> 2;          // 0..63
    const int lc = (t & 3) * 16;    // {0,16,32,48}
    if (!f32) {
        const unsigned short* src = (const unsigned short*)W + (size_t)(k0 + lr) * N + n0 + lc;
        uint4 u0 = *reinterpret_cast<const uint4*>(src);
        uint4 u1 = *reinterpret_cast<const uint4*>(src + 8);
        const unsigned short* us0 = reinterpret_cast<const unsigned short*>(&u0);
        const unsigned short* us1 = reinterpret_cast<const unsigned short*>(&u1);
        #pragma unroll
        for (int j = 0; j < 8; ++j) {
            tile[lr][lc + j]     = bf2f(us0[j]);
            tile[lr][lc + 8 + j] = bf2f(us1[j]);
        }
    } else {
        const float* src = (const float*)W + (size_t)(k0 + lr) * N + n0 + lc;
        #pragma unroll
        for (int q4 = 0; q4 < 4; ++q4) {
            const float4 f = *reinterpret_cast<const float4*>(src + 4 * q4);
            tile[lr][lc + 4*q4 + 0] = f.x;
            tile[lr][lc + 4*q4 + 1] = f.y;
            tile[lr][lc + 4*q4 + 2] = f.z;
            tile[lr][lc + 4*q4 + 3] = f.w;
        }
    }
    __syncthreads();
    unsigned short o[16];
    #pragma unroll
    for (int j = 0; j < 16; ++j) o[j] = f2bu(tile[lc + j][lr]);
    bf16* dst = WT + (size_t)(n0 + lr) * K + k0 + lc;
    *reinterpret_cast<uint4*>(dst)     = *reinterpret_cast<const uint4*>(&o[0]);
    *reinterpret_cast<uint4*>(dst + 8) = *reinterpret_cast<const uint4*>(&o[8]);
}

// WT[n][k] = W[k][n], bf16 out. grid (N/64, K/64), 256 threads.
__global__ __launch_bounds__(256) void transpose_kernel(const void* __restrict__ W,
    bf16* __restrict__ WT, int K, int N, const int* __restrict__ flagp)
{
    __shared__ float tile[64][65];
    ttile(W, WT, K, N, blockIdx.x * 64, blockIdx.y * 64, (*flagp) != 0, tile, threadIdx.x);
}

// Merged prep: [0,2048) xcvt x->Xb; [2048,3072) transpose wq/wk/wv/wo -> WT4;
// [3072,5120) transpose w1 -> W1T, w2 -> W2T. One dispatch, 5120 blocks.
__global__ __launch_bounds__(256) void prep_kernel(
    const void* __restrict__ x, bf16* __restrict__ Xb,
    const void* __restrict__ wq, const void* __restrict__ wk,
    const void* __restrict__ wv, const void* __restrict__ wo, bf16* __restrict__ WT4,
    const void* __restrict__ w1, const void* __restrict__ w2,
    bf16* __restrict__ W1T, bf16* __restrict__ W2T,
    const int* __restrict__ flagp)
{
    __shared__ float tile[64][65];
    const bool f32 = (*flagp) != 0;
    const int id = blockIdx.x;
    if (id < 2048) {
        const size_t i = ((size_t)id * 256 + threadIdx.x) * 8;
        U8 d = ld8bf(x, i, f32);
        *reinterpret_cast<uint4*>(Xb + i) = *reinterpret_cast<const uint4*>(d.v);
        return;
    }
    if (id < 3072) {
        const int local = id - 2048;
        const int which = local >> 8;
        const void* W = (which == 0) ? wq : (which == 1) ? wk : (which == 2) ? wv : wo;
        bf16* WT = WT4 + (size_t)which * D_MODEL * D_MODEL;
        const int rem = local & 255;
        ttile(W, WT, D_MODEL, D_MODEL, (rem & 15) * 64, (rem >> 4) * 64, f32, tile, threadIdx.x);
        return;
    }
    const int local = id - 3072;
    const int z = local >> 10, bid = local & 1023;
    const void* W = z ? w2 : w1;
    bf16* WT = z ? W2T : W1T;
    const int K = z ? D_FF : D_MODEL;
    const int N = z ? D_MODEL : D_FF;
    const int n0 = (z ? (bid & 15) : (bid & 63)) * 64;
    const int k0 = (z ? (bid >> 4) : (bid >> 6)) * 64;
    ttile(W, WT, K, N, n0, k0, f32, tile, threadIdx.x);
}

// MFMA GEMM: C bf16 = A[M,K] @ BT[N,K]^T (+bias)(+relu). 128x128 tile, 4 waves,
// BK=64, global_load_lds staging, XOR-swizzled unpadded LDS.
// XCD-chunked block swizzle (T1): consecutive hardware lin ids round-robin
// XCDs; remap so each XCD owns a contiguous rid chunk with rowb fastest
// (shared B-panels stay L2-resident). Requires nwg % 8 == 0 (all launches).
// NMAT>1: fused QKV (N==1024/mat). which==2 (V) writes TRANSPOSED layout
// VT[((b*16+h)*64+d)*2048 + s] directly. SPLITK>1: kslice -> C + z*M*N.
template<bool RELU, bool BIAS, int NMAT, int SPLITK>
__global__ __launch_bounds__(256) void mgemm_kernel(const bf16* __restrict__ A,
    const bf16* __restrict__ BT, const void* __restrict__ bias,
    bf16* __restrict__ C, int M, int N, int K, const int* __restrict__ flagp)
{
    const bool inF32 = (*flagp) != 0;

    __shared__ unsigned short sA[128 * 64];   // 16 KB
    __shared__ unsigned short sB[128 * 64];   // 16 KB

    // XCD-chunked swizzle (bijective, nwg % 8 == 0)
    const int gx  = gridDim.x, gy = gridDim.y;
    const int nwg = gx * gy * gridDim.z;
    const int lin = blockIdx.x + gx * (blockIdx.y + gy * blockIdx.z);
    const int rid = (lin & 7) * (nwg >> 3) + (lin >> 3);
    const int by  = rid % gy;          // row tile (fastest -> B-panel reuse)
    const int tq  = rid / gy;
    const int bx  = tq % gx;
    const int bz  = tq / gx;

    int which = 0, colb = bx;
    if (NMAT > 1) { which = bx >> 3; colb = bx & 7; }
    const int kslice = (SPLITK > 1) ? bz : 0;
    const int Kspan  = K / SPLITK;
    const int kbase  = kslice * Kspan;
    const bf16* Bp = BT + (size_t)which * N * K;
    bf16*       Cp = C  + (size_t)which * M * N + (size_t)kslice * M * N;

    const int row0 = by * 128;
    const int col0 = colb * 128;

    const int t    = threadIdx.x;
    const int wave = t >> 6;
    const int lane = t & 63;
    const int lm   = lane & 15;
    const int q    = lane >> 4;
    const int wm   = (wave & 1) * 64;
    const int wn   = (wave >> 1) * 64;

    facc4 acc[4][4];
    #pragma unroll
    for (int i = 0; i < 4; ++i)
        #pragma unroll
        for (int j = 0; j < 4; ++j)
            acc[i][j] = (facc4){0.f, 0.f, 0.f, 0.f};

    for (int k0 = kbase; k0 < kbase + Kspan; k0 += 64) {
        __syncthreads();
        #pragma unroll
        for (int j = 0; j < 4; ++j) {
            const int ch = (wave * 4 + j) * 64 + lane;   // 0..1023
            const int r  = ch >> 3;
            const int cs = ch & 7;
            const int c  = cs ^ (r & 7);
            gld16(A  + (size_t)(row0 + r) * K + k0 + 8 * c, &sA[(wave * 4 + j) * 512]);
            gld16(Bp + (size_t)(col0 + r) * K + k0 + 8 * c, &sB[(wave * 4 + j) * 512]);
        }
        __syncthreads();

        #pragma unroll
        for (int kk = 0; kk < 64; kk += 32) {
            const int cr = (kk >> 3) + q;
            frag8 af[4], bfr[4];
            #pragma unroll
            for (int im = 0; im < 4; ++im) {
                const int m = wm + 16 * im + lm;
                af[im] = *reinterpret_cast<const frag8*>(&sA[m * 64 + ((cr ^ (m & 7)) << 3)]);
            }
            #pragma unroll
            for (int in = 0; in < 4; ++in) {
                const int n = wn + 16 * in + lm;
                bfr[in] = *reinterpret_cast<const frag8*>(&sB[n * 64 + ((cr ^ (n & 7)) << 3)]);
            }
            #pragma unroll
            for (int im = 0; im < 4; ++im)
                #pragma unroll
                for (int in = 0; in < 4; ++in)
                    acc[im][in] = __builtin_amdgcn_mfma_f32_16x16x32_bf16(af[im], bfr[in], acc[im][in], 0, 0, 0);
        }
    }

    if (NMAT > 1 && which == 2) {
        // V slot gets V^T directly: row = token (b*2048+s), col = h*64+d.
        // r=0..3 are consecutive s -> packed uint2 stores. M==4096, N==1024.
        #pragma unroll
        for (int in = 0; in < 4; ++in) {
            const int col = col0 + wn + 16*in + lm;     // 0..1023
            const int hh = col >> 6, dd = col & 63;
            #pragma unroll
            for (int im = 0; im < 4; ++im) {
                const int rowb = row0 + wm + 16*im + 4*q;   // +r
                const int bb = rowb >> 11, ss = rowb & 2047;
                union { uint2 v; unsigned u[2]; } ov;
                ov.u[0] = cvtpk_bf16(acc[im][in][0], acc[im][in][1]);
                ov.u[1] = cvtpk_bf16(acc[im][in][2], acc[im][in][3]);
                *reinterpret_cast<uint2*>(Cp + ((size_t)((bb * 16 + hh) * 64 + dd)) * 2048 + ss) = ov.v;
            }
        }
        return;
    }

    #pragma unroll
    for (int in = 0; in < 4; ++in) {
        const int col = col0 + wn + 16*in + lm;
        float bv = 0.f;
        if (BIAS && kslice == 0) bv = ld1(bias, col, inF32);
        #pragma unroll
        for (int im = 0; im < 4; ++im) {
            #pragma unroll
            for (int r = 0; r < 4; ++r) {
                const int row = row0 + wm + 16*im + 4*q + r;
                float v = acc[im][in][r] + bv;
                if (RELU) v = fmaxf(v, 0.f);
                Cp[(size_t)row * N + col] = __float2bfloat16(v);
            }
        }
    }
}

// MFMA flash attention v9: R4 geometry (128q block, 4 waves x 32q, KTILE=128,
// 16-tile loop, LDS 72 KB, 2 blocks/CU) + XCD-chunked role swizzle (K/V 2 MB
// L2-resident; FETCH 69.7 -> 12.4 MB) + local-max defer. Dbuf staging,
// 1 barrier/tile, in-register P, permlane routing, cvt_pk packs,
// exp2-domain softmax, setprio around MFMA. Mask loads int4-vectorized.
__global__ __launch_bounds__(256, 2) void fattn_kernel(
    const bf16* __restrict__ Qg, const bf16* __restrict__ Kg,
    const bf16* __restrict__ VTg, const int* __restrict__ mask,
    bf16* __restrict__ ctx)
{
    __shared__ unsigned short sK[2][128 * 64];    // 2 x 16 KB, swizzled [kk][d]
    __shared__ unsigned short sV[2][64 * 128];    // 2 x 16 KB, swizzled [d][kk]
    __shared__ __align__(16) float madd[SEQ];     // 8 KB, log2-domain mask add

    const int t    = threadIdx.x;                 // 0..255
    // XCD-chunked role decode (512 blocks = 8 XCDs x 64 roles, bijective).
    const int lin  = blockIdx.x + 16 * (blockIdx.y + 16 * blockIdx.z);
    const int rid  = (lin & 7) * 64 + (lin >> 3);
    const int qt   = rid & 15;
    const int h    = (rid >> 4) & 15;
    const int b    = rid >> 8;
    const int q0   = qt * 128;
    const int bh   = b * N_HEADS + h;
    const int wave = t >> 6;                      // 0..3
    const int lane = t & 63;
    const int lm   = lane & 15;
    const int qd   = lane >> 4;
    const bool qo  = (qd & 1) != 0;

    // log2-domain: S2 = S*(0.125*log2e) + madd; p = exp2(S2 - m).
    const float SCL = 0.18033688011112042f;   // 0.125 * log2(e)

    auto stage = [&](int bi, int kt) {
        const int k0 = kt * KTILE;
        #pragma unroll
        for (int j = 0; j < 4; ++j) {
            const int ch = (wave * 4 + j) * 64 + lane;   // 0..1023
            const int rK = ch >> 3, cK = (ch & 7) ^ (rK & 7);
            gld16(Kg + ((size_t)(b * SEQ + k0 + rK)) * D_MODEL + h * DK + 8 * cK,
                  &sK[bi][(wave * 4 + j) * 512]);
            const int rV = ch >> 4, cV = (ch & 15) ^ (rV & 15);
            gld16(VTg + ((size_t)(bh * DK + rV)) * SEQ + k0 + 8 * cV,
                  &sV[bi][(wave * 4 + j) * 512]);
        }
    };

    // prologue: stage tile 0 into buffer 0; fill mask row while loads fly
    stage(0, 0);
    #pragma unroll
    for (int i = 0; i < SEQ / (256 * 4); ++i) {
        const int idx = (i * 256 + t) * 4;
        const int4 mv = *reinterpret_cast<const int4*>(&mask[b * SEQ + idx]);
        madd[idx + 0] = (mv.x == 0) ? -1.442695e9f : 0.f;
        madd[idx + 1] = (mv.y == 0) ? -1.442695e9f : 0.f;
        madd[idx + 2] = (mv.z == 0) ? -1.442695e9f : 0.f;
        madd[idx + 3] = (mv.w == 0) ? -1.442695e9f : 0.f;
    }

    // Q fragments (B-operand) direct from global, once per block.
    frag8 qf[2][2];
    #pragma unroll
    for (int s = 0; s < 2; ++s) {
        const bf16* qsrc = Qg + ((size_t)(b * SEQ + q0 + 32 * wave + 16 * s + lm)) * D_MODEL + h * DK;
        qf[s][0] = *reinterpret_cast<const frag8*>(qsrc + 8 * qd);
        qf[s][1] = *reinterpret_cast<const frag8*>(qsrc + 32 + 8 * qd);
    }

    facc4 accO[2][4];
    #pragma unroll
    for (int s = 0; s < 2; ++s)
        #pragma unroll
        for (int in = 0; in < 4; ++in) accO[s][in] = (facc4){0.f, 0.f, 0.f, 0.f};
    float m_r[2] = {-1e30f, -1e30f}, l_r[2] = {0.f, 0.f};

    for (int kt = 0; kt < SEQ / KTILE; ++kt) {
        const int cur = kt & 1;
        const int k0  = kt * KTILE;
        // drains vmcnt->0 (stage(cur) complete) + closes prev tile's LDS reads
        __syncthreads();
        if (kt + 1 < SEQ / KTILE) stage(cur ^ 1, kt + 1);

        // ---- S^T = K @ Q^T (swapped operands); each kf read feeds both q-sets ----
        facc4 accST[2][8];
        #pragma unroll
        for (int s = 0; s < 2; ++s)
            #pragma unroll
            for (int i = 0; i < 8; ++i) accST[s][i] = (facc4){0.f, 0.f, 0.f, 0.f};
        __builtin_amdgcn_s_setprio(1);
        #pragma unroll
        for (int i = 0; i < 8; ++i) {
            #pragma unroll
            for (int s2 = 0; s2 < 2; ++s2) {
                const int cr = 4 * s2 + qd;
                frag8 kf = *reinterpret_cast<const frag8*>(
                    &sK[cur][(16 * i + lm) * 64 + ((cr ^ (lm & 7)) << 3)]);
                accST[0][i] = __builtin_amdgcn_mfma_f32_16x16x32_bf16(kf, qf[0][s2], accST[0][i], 0, 0, 0);
                accST[1][i] = __builtin_amdgcn_mfma_f32_16x16x32_bf16(kf, qf[1][s2], accST[1][i], 0, 0, 0);
            }
        }
        __builtin_amdgcn_s_setprio(0);

        // ---- row-local softmax (log2 domain); 4 independent max chains/set ----
        facc4 vmx[2];
        #pragma unroll
        for (int s = 0; s < 2; ++s) vmx[s] = (facc4){-1e30f, -1e30f, -1e30f, -1e30f};
        #pragma unroll
        for (int i = 0; i < 8; ++i) {
            const facc4 mv = *reinterpret_cast<const facc4*>(&madd[k0 + 16 * i + 4 * qd]);
            #pragma unroll
            for (int s = 0; s < 2; ++s) {
                #pragma unroll
                for (int r = 0; r < 4; ++r) {
                    accST[s][i][r] = fmaf(accST[s][i][r], SCL, mv[r]);
                    vmx[s][r] = fmaxf(vmx[s][r], accST[s][i][r]);
                }
            }
        }
        float mn[2], alpha[2] = {1.f, 1.f};
        bool resc[2];
        #pragma unroll
        for (int s = 0; s < 2; ++s) {
            // local max only; cross-lane reduce deferred to the rare branch
            const float mloc = fmaxf(fmaxf(vmx[s][0], vmx[s][1]), fmaxf(vmx[s][2], vmx[s][3]));
            // defer-max (T13): if every lane's local growth <= 8 nats (11.54 log2),
            // keep old m (values bounded by 2^11.54) -- no reduce, no rescale.
            const bool skip = __all(mloc - m_r[s] <= 11.54f) != 0;
            resc[s] = !skip;
            if (skip) {
                mn[s] = m_r[s];
            } else {
                float m0 = mloc;
                m0 = fmaxf(m0, __shfl_xor(m0, 16));
                m0 = fmaxf(m0, __shfl_xor(m0, 32));
                mn[s] = fmaxf(m_r[s], m0);
                alpha[s] = __builtin_amdgcn_exp2f(m_r[s] - mn[s]);
                m_r[s] = mn[s];
            }
        }

        // p = exp2(s2 - mn); pack via v_cvt_pk_bf16_f32 (1 op / pair);
        // 4 independent partial-sum chains per set.
        unsigned up[2][8][2];
        facc4 ps4[2];
        #pragma unroll
        for (int s = 0; s < 2; ++s) ps4[s] = (facc4){0.f, 0.f, 0.f, 0.f};
        #pragma unroll
        for (int s = 0; s < 2; ++s) {
            #pragma unroll
            for (int i = 0; i < 8; ++i) {
                const float p0 = __builtin_amdgcn_exp2f(accST[s][i][0] - mn[s]);
                const float p1 = __builtin_amdgcn_exp2f(accST[s][i][1] - mn[s]);
                const float p2 = __builtin_amdgcn_exp2f(accST[s][i][2] - mn[s]);
                const float p3 = __builtin_amdgcn_exp2f(accST[s][i][3] - mn[s]);
                ps4[s][0] += p0; ps4[s][1] += p1; ps4[s][2] += p2; ps4[s][3] += p3;
                up[s][i][0] = cvtpk_bf16(p0, p1);
                up[s][i][1] = cvtpk_bf16(p2, p3);
            }
        }
        #pragma unroll
        for (int s = 0; s < 2; ++s) {
            float ps = (ps4[s][0] + ps4[s][1]) + (ps4[s][2] + ps4[s][3]);
            ps += __shfl_xor(ps, 16);
            ps += __shfl_xor(ps, 32);
            if (resc[s]) {
                l_r[s] = l_r[s] * alpha[s] + ps;
                #pragma unroll
                for (int in = 0; in < 4; ++in)
                    #pragma unroll
                    for (int r = 0; r < 4; ++r) accO[s][in][r] *= alpha[s];
            } else {
                l_r[s] += ps;
            }
        }

        // ---- O^T += V^T @ P^T; each vf read feeds both q-sets ----
        __builtin_amdgcn_s_setprio(1);
        #pragma unroll
        for (int c = 0; c < 4; ++c) {
            union { frag8 f; unsigned u[4]; } pf0_, pf1_;
            #pragma unroll
            for (int s = 0; s < 2; ++s) {
                unsigned a0 = up[s][2*c][0],     a1 = up[s][2*c][1];
                unsigned b0 = up[s][2*c + 1][0], b1 = up[s][2*c + 1][1];
                asm("v_permlane32_swap_b32 %0, %1" : "+v"(a0), "+v"(b0));
                asm("v_permlane32_swap_b32 %0, %1" : "+v"(a1), "+v"(b1));
                const unsigned t0 = qo ? a0 : b0;
                const unsigned t1 = qo ? a1 : b1;
                const unsigned r0 = __shfl_xor(t0, 16);
                const unsigned r1 = __shfl_xor(t1, 16);
                unsigned u0 = qo ? r0 : a0;   // kk = 32c+8qd+0,1
                unsigned u1 = qo ? r1 : a1;   // kk = 32c+8qd+2,3
                unsigned u2 = qo ? b0 : r0;  // kk = 32c+8qd+4,5
                unsigned u3 = qo ? b1 : r1;  // kk = 32c+8qd+6,7
                if (s == 0) { pf0_.u[0]=u0; pf0_.u[1]=u1; pf0_.u[2]=u2; pf0_.u[3]=u3; }
                else        { pf1_.u[0]=u0; pf1_.u[1]=u1; pf1_.u[2]=u2; pf1_.u[3]=u3; }
            }
            #pragma unroll
            for (int in = 0; in < 4; ++in) {
                const int cr = 4 * c + qd;
                frag8 vf = *reinterpret_cast<const frag8*>(
                    &sV[cur][(16 * in + lm) * 128 + ((cr ^ lm) << 3)]);
                accO[0][in] = __builtin_amdgcn_mfma_f32_16x16x32_bf16(vf, pf0_.f, accO[0][in], 0, 0, 0);
                accO[1][in] = __builtin_amdgcn_mfma_f32_16x16x32_bf16(vf, pf1_.f, accO[1][in], 0, 0, 0);
            }
        }
        __builtin_amdgcn_s_setprio(0);
    }

    // Lane (lm,qd) holds O[q = set_s + lm][d = 16*in + 4*qd + r]; packed 8B stores.
    #pragma unroll
    for (int s = 0; s < 2; ++s) {
        const float invl = 1.f / l_r[s];
        bf16* crow = ctx + ((size_t)(b * SEQ + q0 + 32 * wave + 16 * s + lm)) * D_MODEL + h * DK;
        #pragma unroll
        for (int in = 0; in < 4; ++in) {
            union { uint2 v; unsigned u[2]; } ov;
            ov.u[0] = cvtpk_bf16(accO[s][in][0] * invl, accO[s][in][1] * invl);
            ov.u[1] = cvtpk_bf16(accO[s][in][2] * invl, accO[s][in][3] * invl);
            *reinterpret_cast<uint2*>(crow + 16 * in + 4 * qd) = ov.v;
        }
    }
}

// LayerNorm v3 (G13): 128 threads/row, row register-resident (8 els/thread,
// vector loads incl. alpha/bias), wave shfl reduce + 2-entry LDS combine,
// cvt_pk packed stores. y = alpha*(v-mean)/(std+eps)+bias, ddof=1.
template<bool BASE_WS, bool OUT_WS>
__global__ __launch_bounds__(128) void ln_kernel(const void* __restrict__ base,
    const bf16* __restrict__ addv, const bf16* __restrict__ addv2,
    const void* __restrict__ alpha, const void* __restrict__ bias,
    void* __restrict__ outp, const int* __restrict__ flagp)
{
    const bool inF32 = (*flagp) != 0;
    __shared__ float red[2];
    __shared__ float red2[2];
    const int row = blockIdx.x, t = threadIdx.x;
    const size_t off = (size_t)row * D_MODEL + t * 8;

    float v[8];
    {
        const U8 bz = ld8bf(base, off, BASE_WS ? false : inF32);
        uint4 a1 = *reinterpret_cast<const uint4*>(addv + off);
        const unsigned short* a1s = reinterpret_cast<const unsigned short*>(&a1);
        #pragma unroll
        for (int j = 0; j < 8; ++j) v[j] = bf2f(bz.v[j]) + bf2f(a1s[j]);
        if (addv2) {
            uint4 a2 = *reinterpret_cast<const uint4*>(addv2 + off);
            const unsigned short* a2s = reinterpret_cast<const unsigned short*>(&a2);
            #pragma unroll
            for (int j = 0; j < 8; ++j) v[j] += bf2f(a2s[j]);
        }
    }

    float s = ((v[0]+v[1]) + (v[2]+v[3])) + ((v[4]+v[5]) + (v[6]+v[7]));
    #pragma unroll
    for (int o = 1; o < 64; o <<= 1) s += __shfl_xor(s, o);
    if ((t & 63) == 0) red[t >> 6] = s;
    __syncthreads();
    const float mean = (red[0] + red[1]) * (1.f / (float)D_MODEL);

    float sq = 0.f;
    #pragma unroll
    for (int j = 0; j < 8; ++j) { const float d = v[j] - mean; sq += d * d; }
    #pragma unroll
    for (int o = 1; o < 64; o <<= 1) sq += __shfl_xor(sq, o);
    if ((t & 63) == 0) red2[t >> 6] = sq;
    __syncthreads();
    const float var = (red2[0] + red2[1]) * (1.f / (float)(D_MODEL - 1));
    const float inv = 1.f / (sqrtf(var) + LN_EPS);

    float av[8], bv[8];
    ld8f(alpha, t * 8, inF32, av);
    ld8f(bias,  t * 8, inF32, bv);
    float y[8];
    #pragma unroll
    for (int j = 0; j < 8; ++j)
        y[j] = av[j] * (v[j] - mean) * inv + bv[j];

    if (OUT_WS || !inF32) {
        union { uint4 u; unsigned w[4]; } o_;
        o_.w[0] = cvtpk_bf16(y[0], y[1]);
        o_.w[1] = cvtpk_bf16(y[2], y[3]);
        o_.w[2] = cvtpk_bf16(y[4], y[5]);
        o_.w[3] = cvtpk_bf16(y[6], y[7]);
        *reinterpret_cast<uint4*>((bf16*)outp + off) = o_.u;
    } else {
        float* op = (float*)outp + off;
        const float4 f0 = {y[0], y[1], y[2], y[3]};
        const float4 f1 = {y[4], y[5], y[6], y[7]};
        *reinterpret_cast<float4*>(op)     = f0;
        *reinterpret_cast<float4*>(op + 4) = f1;
    }
}

extern "C" void kernel_launch(void* const* d_in, const int* in_sizes, int n_in,
                              void* d_out, int out_size, void* d_ws, size_t ws_size,
                              hipStream_t stream)
{
    const void* x    = d_in[0];
    const int*  mask = (const int*)d_in[1];
    const void* wq   = d_in[2];
    const void* wk   = d_in[3];
    const void* wv   = d_in[4];
    const void* wo   = d_in[5];
    const void* wo_b = d_in[6];
    const void* w1   = d_in[7];
    const void* b1   = d_in[8];
    const void* w2   = d_in[9];
    const void* b2   = d_in[10];
    const void* al1  = d_in[11];
    const void* bi1  = d_in[12];
    const void* al2  = d_in[13];
    const void* bi2  = d_in[14];

    const size_t MB = 1024 * 1024;
    char* ws = (char*)d_ws;
    const bool BIG = ws_size >= 64 * MB + 4096;     // R8 confirmed this branch runs
    if (!BIG && ws_size < 56 * MB + 4096) return;   // loud fail: out stays 0

    if (BIG) {
        // 64 MB plan. QKV writes Q[0,8) K[8,16) and V^T DIRECTLY into [16,24).
        //  [24,32) Xb (QKV input)
        //  [32,40) WT4 (wq,wk,wv,wo) -> dead after oproj -> X20 [32,40)
        //  [40,48) W1T -> dead after FF1 -> X21 [40,48)
        //  [48,56) W2T
        //  [56,64) CTXb -> dead after oproj -> X1b [56,64)
        //  ATT0 [0,8) / ATT1 [8,16) over dead Qb/Kb; FFb [0,32) after ln1
        bf16* Qb   = (bf16*)(ws + 0 * MB);
        bf16* Kb   = (bf16*)(ws + 8 * MB);
        bf16* VTb  = (bf16*)(ws + 16 * MB);
        bf16* Xb   = (bf16*)(ws + 24 * MB);
        bf16* WT4  = (bf16*)(ws + 32 * MB);
        bf16* WOT  = WT4 + (size_t)3 * D_MODEL * D_MODEL;
        bf16* W1T  = (bf16*)(ws + 40 * MB);
        bf16* W2T  = (bf16*)(ws + 48 * MB);
        bf16* CTXb = (bf16*)(ws + 56 * MB);
        bf16* ATT0 = (bf16*)(ws + 0 * MB);
        bf16* ATT1 = (bf16*)(ws + 8 * MB);
        bf16* X1b  = (bf16*)(ws + 56 * MB);
        bf16* FFb  = (bf16*)(ws + 0 * MB);
        bf16* X20  = (bf16*)(ws + 32 * MB);
        bf16* X21  = (bf16*)(ws + 40 * MB);
        int*  flagp = (int*)(ws + 64 * MB);

        probe_kernel<<<1, 256, 0, stream>>>(x, flagp);
        prep_kernel<<<dim3(5120), 256, 0, stream>>>(x, Xb, wq, wk, wv, wo, WT4,
                                                    w1, w2, W1T, W2T, flagp);

        mgemm_kernel<false, false, 3, 1><<<dim3(24, 32), 256, 0, stream>>>(
            Xb, WT4, nullptr, Qb, ROWS, D_MODEL, D_MODEL, flagp);

        fattn_kernel<<<dim3(SEQ / 128, N_HEADS, BATCH), 256, 0, stream>>>(Qb, Kb, VTb, mask, CTXb);

        mgemm_kernel<false, true, 1, 2><<<dim3(8, 32, 2), 256, 0, stream>>>(
            CTXb, WOT, wo_b, ATT0, ROWS, D_MODEL, D_MODEL, flagp);
        ln_kernel<false, true><<<ROWS, 128, 0, stream>>>(x, ATT0, ATT1, al1, bi1, X1b, flagp);

        mgemm_kernel<true, true, 1, 1><<<dim3(32, 32), 256, 0, stream>>>(
            X1b, W1T, b1, FFb, ROWS, D_FF, D_MODEL, flagp);

        mgemm_kernel<false, true, 1, 2><<<dim3(8, 32, 2), 256, 0, stream>>>(
            FFb, W2T, b2, X20, ROWS, D_MODEL, D_FF, flagp);
        ln_kernel<true, false><<<ROWS, 128, 0, stream>>>(X1b, X20, X21, al2, bi2, d_out, flagp);
    } else {
        // 56 MB fallback (no split-K). QKV writes V^T directly into [16,24).
        bf16* Qb    = (bf16*)(ws + 0 * MB);
        bf16* Kb    = (bf16*)(ws + 8 * MB);
        bf16* VTb   = (bf16*)(ws + 16 * MB);
        bf16* Xb    = (bf16*)(ws + 24 * MB);
        bf16* WQKVT = (bf16*)(ws + 32 * MB);
        bf16* CTXb  = (bf16*)(ws + 32 * MB);
        bf16* W2T   = (bf16*)(ws + 32 * MB);
        bf16* WOT   = (bf16*)(ws + 0 * MB);
        bf16* ATT0  = (bf16*)(ws + 48 * MB);
        bf16* W1T   = (bf16*)(ws + 48 * MB);
        bf16* X20   = (bf16*)(ws + 48 * MB);
        bf16* X1b   = (bf16*)(ws + 40 * MB);
        bf16* FFb   = (bf16*)(ws + 0 * MB);
        int*  flagp = (int*)(ws + 56 * MB);

        probe_kernel<<<1, 256, 0, stream>>>(x, flagp);
        xcvt_kernel<<<dim3(ROWS * D_MODEL / 2048), 256, 0, stream>>>(x, Xb, flagp);

        transpose_kernel<<<dim3(16, 16), 256, 0, stream>>>(wq, WQKVT,           D_MODEL, D_MODEL, flagp);
        transpose_kernel<<<dim3(16, 16), 256, 0, stream>>>(wk, WQKVT + 1048576, D_MODEL, D_MODEL, flagp);
        transpose_kernel<<<dim3(16, 16), 256, 0, stream>>>(wv, WQKVT + 2097152, D_MODEL, D_MODEL, flagp);

        mgemm_kernel<false, false, 3, 1><<<dim3(24, 32), 256, 0, stream>>>(
            Xb, WQKVT, nullptr, Qb, ROWS, D_MODEL, D_MODEL, flagp);

        fattn_kernel<<<dim3(SEQ / 128, N_HEADS, BATCH), 256, 0, stream>>>(Qb, Kb, VTb, mask, CTXb);

        transpose_kernel<<<dim3(16, 16), 256, 0, stream>>>(wo, WOT, D_MODEL, D_MODEL, flagp);
        mgemm_kernel<false, true, 1, 1><<<dim3(8, 32), 256, 0, stream>>>(
            CTXb, WOT, wo_b, ATT0, ROWS, D_MODEL, D_MODEL, flagp);
        ln_kernel<false, true><<<ROWS, 128, 0, stream>>>(x, ATT0, nullptr, al1, bi1, X1b, flagp);

        transpose_kernel<<<dim3(64, 16), 256, 0, stream>>>(w1, W1T, D_MODEL, D_FF, flagp);
        mgemm_kernel<true, true, 1, 1><<<dim3(32, 32), 256, 0, stream>>>(
            X1b, W1T, b1, FFb, ROWS, D_FF, D_MODEL, flagp);

        transpose_kernel<<<dim3(16, 64), 256, 0, stream>>>(w2, W2T, D_FF, D_MODEL, flagp);
        mgemm_kernel<false, true, 1, 1><<<dim3(8, 32), 256, 0, stream>>>(
            FFb, W2T, b2, X20, ROWS, D_MODEL, D_FF, flagp);
        ln_kernel<true, false><<<ROWS, 128, 0, stream>>>(X1b, X20, nullptr, al2, bi2, d_out, flagp);
    }
}

// Round 11
// 356.547 us; speedup vs baseline: 1.0194x; 1.0194x over previous
//
#include <hip/hip_runtime.h>
#include <hip/hip_bf16.h>

#define D_MODEL 1024
#define N_HEADS 16
#define DK      64
#define SEQ     2048
#define BATCH   2
#define D_FF    4096
#define ROWS    (BATCH*SEQ)   // 4096
#define LN_EPS  1e-6f
#define KTILE   128           // fattn K-tile

typedef __hip_bfloat16 bf16;
typedef __attribute__((ext_vector_type(8))) short frag8;   // 8 bf16 (MFMA A/B)
typedef __attribute__((ext_vector_type(4))) float facc4;   // 4 f32 (MFMA C/D)

__device__ inline float bf2f(unsigned short u){ return __uint_as_float(((unsigned)u) << 16); }
__device__ inline float toF(bf16 v){ return __bfloat162float(v); }
__device__ inline unsigned short f2bu(float f){ bf16 h = __float2bfloat16(f); return *reinterpret_cast<unsigned short*>(&h); }

// 2 f32 -> packed 2x bf16 (RNE), single instruction on gfx950.
__device__ inline unsigned cvtpk_bf16(float lo, float hi){
    unsigned r;
    asm("v_cvt_pk_bf16_f32 %0, %1, %2" : "=v"(r) : "v"(lo), "v"(hi));
    return r;
}

__device__ inline float ld1(const void* p, size_t idx, bool f32) {
    return f32 ? ((const float*)p)[idx] : toF(((const bf16*)p)[idx]);
}

struct U8 { unsigned short v[8]; };
__device__ inline U8 ld8bf(const void* p, size_t idx, bool f32) {
    U8 r;
    if (!f32) {
        *reinterpret_cast<uint4*>(r.v) = *reinterpret_cast<const uint4*>((const unsigned short*)p + idx);
    } else {
        const float* f = (const float*)p + idx;
        const float4 a = *reinterpret_cast<const float4*>(f);
        const float4 b = *reinterpret_cast<const float4*>(f + 4);
        r.v[0]=f2bu(a.x); r.v[1]=f2bu(a.y); r.v[2]=f2bu(a.z); r.v[3]=f2bu(a.w);
        r.v[4]=f2bu(b.x); r.v[5]=f2bu(b.y); r.v[6]=f2bu(b.z); r.v[7]=f2bu(b.w);
    }
    return r;
}

// 8 f32 values from alpha/bias-style vectors, dtype-aware, vectorized (G13).
__device__ inline void ld8f(const void* p, int idx, bool f32, float* o) {
    if (!f32) {
        uint4 u = *reinterpret_cast<const uint4*>((const unsigned short*)p + idx);
        const unsigned short* us = reinterpret_cast<const unsigned short*>(&u);
        #pragma unroll
        for (int j = 0; j < 8; ++j) o[j] = bf2f(us[j]);
    } else {
        const float* f = (const float*)p + idx;
        const float4 a = *reinterpret_cast<const float4*>(f);
        const float4 b = *reinterpret_cast<const float4*>(f + 4);
        o[0]=a.x; o[1]=a.y; o[2]=a.z; o[3]=a.w;
        o[4]=b.x; o[5]=b.y; o[6]=b.z; o[7]=b.w;
    }
}

// Async global->LDS, 16B/lane. LDS dst is wave-uniform base; lane i -> dst+i*16B.
__device__ inline void gld16(const void* g, void* l) {
    __builtin_amdgcn_global_load_lds(
        reinterpret_cast<const __attribute__((address_space(1))) void*>(
            reinterpret_cast<uintptr_t>(g)),
        reinterpret_cast<__attribute__((address_space(3))) void*>(
            (unsigned int)reinterpret_cast<uintptr_t>(l)),
        16, 0, 0);
}

// Dtype probe: fp32 bits misread as bf16 give Inf/NaN/huge values.
__global__ void probe_kernel(const void* __restrict__ xp, int* __restrict__ flag) {
    __shared__ int hit;
    if (threadIdx.x == 0) hit = 0;
    __syncthreads();
    const bf16* p = (const bf16*)xp;
    int bad = 0;
    for (int i = threadIdx.x; i < 8192; i += 256) {
        float v = fabsf(toF(p[i]));
        if (!(v <= 1e5f)) bad = 1;
    }
    if (bad) atomicOr(&hit, 1);
    __syncthreads();
    if (threadIdx.x == 0) *flag = hit;   // 1 => inputs are fp32
}

// x (flag dtype) -> canonical bf16 ws buffer. 8 elems/thread.
__global__ __launch_bounds__(256) void xcvt_kernel(const void* __restrict__ x,
    bf16* __restrict__ out, const int* __restrict__ flagp)
{
    const bool f32 = (*flagp) != 0;
    const size_t i = ((size_t)blockIdx.x * 256 + threadIdx.x) * 8;
    U8 d = ld8bf(x, i, f32);
    *reinterpret_cast<uint4*>(out + i) = *reinterpret_cast<const uint4*>(d.v);
}

// Shared 64x64 transpose tile body: W[k0+.., n0+..] -> WT[n0+..][k0+..].
__device__ inline void ttile(const void* W, bf16* WT, int K, int N,
                             int n0, int k0, bool f32, float (*tile)[65], int t)
{
    const int lr = t >> 2;          // 0..63
    const int lc = (t & 3) * 16;    // {0,16,32,48}
    if (!f32) {
        const unsigned short* src = (const unsigned short*)W + (size_t)(k0 + lr) * N + n0 + lc;
        uint4 u0 = *reinterpret_cast<const uint4*>(src);
        uint4 u1 = *reinterpret_cast<const uint4*>(src + 8);
        const unsigned short* us0 = reinterpret_cast<const unsigned short*>(&u0);
        const unsigned short* us1 = reinterpret_cast<const unsigned short*>(&u1);
        #pragma unroll
        for (int j = 0; j < 8; ++j) {
            tile[lr][lc + j]     = bf2f(us0[j]);
            tile[lr][lc + 8 + j] = bf2f(us1[j]);
        }
    } else {
        const float* src = (const float*)W + (size_t)(k0 + lr) * N + n0 + lc;
        #pragma unroll
        for (int q4 = 0; q4 < 4; ++q4) {
            const float4 f = *reinterpret_cast<const float4*>(src + 4 * q4);
            tile[lr][lc + 4*q4 + 0] = f.x;
            tile[lr][lc + 4*q4 + 1] = f.y;
            tile[lr][lc + 4*q4 + 2] = f.z;
            tile[lr][lc + 4*q4 + 3] = f.w;
        }
    }
    __syncthreads();
    unsigned short o[16];
    #pragma unroll
    for (int j = 0; j < 16; ++j) o[j] = f2bu(tile[lc + j][lr]);
    bf16* dst = WT + (size_t)(n0 + lr) * K + k0 + lc;
    *reinterpret_cast<uint4*>(dst)     = *reinterpret_cast<const uint4*>(&o[0]);
    *reinterpret_cast<uint4*>(dst + 8) = *reinterpret_cast<const uint4*>(&o[8]);
}

// WT[n][k] = W[k][n], bf16 out. grid (N/64, K/64), 256 threads.
__global__ __launch_bounds__(256) void transpose_kernel(const void* __restrict__ W,
    bf16* __restrict__ WT, int K, int N, const int* __restrict__ flagp)
{
    __shared__ float tile[64][65];
    ttile(W, WT, K, N, blockIdx.x * 64, blockIdx.y * 64, (*flagp) != 0, tile, threadIdx.x);
}

// Merged prep: [0,2048) xcvt x->Xb; [2048,3072) transpose wq/wk/wv/wo -> WT4;
// [3072,5120) transpose w1 -> W1T, w2 -> W2T. One dispatch, 5120 blocks.
__global__ __launch_bounds__(256) void prep_kernel(
    const void* __restrict__ x, bf16* __restrict__ Xb,
    const void* __restrict__ wq, const void* __restrict__ wk,
    const void* __restrict__ wv, const void* __restrict__ wo, bf16* __restrict__ WT4,
    const void* __restrict__ w1, const void* __restrict__ w2,
    bf16* __restrict__ W1T, bf16* __restrict__ W2T,
    const int* __restrict__ flagp)
{
    __shared__ float tile[64][65];
    const bool f32 = (*flagp) != 0;
    const int id = blockIdx.x;
    if (id < 2048) {
        const size_t i = ((size_t)id * 256 + threadIdx.x) * 8;
        U8 d = ld8bf(x, i, f32);
        *reinterpret_cast<uint4*>(Xb + i) = *reinterpret_cast<const uint4*>(d.v);
        return;
    }
    if (id < 3072) {
        const int local = id - 2048;
        const int which = local >> 8;
        const void* W = (which == 0) ? wq : (which == 1) ? wk : (which == 2) ? wv : wo;
        bf16* WT = WT4 + (size_t)which * D_MODEL * D_MODEL;
        const int rem = local & 255;
        ttile(W, WT, D_MODEL, D_MODEL, (rem & 15) * 64, (rem >> 4) * 64, f32, tile, threadIdx.x);
        return;
    }
    const int local = id - 3072;
    const int z = local >> 10, bid = local & 1023;
    const void* W = z ? w2 : w1;
    bf16* WT = z ? W2T : W1T;
    const int K = z ? D_FF : D_MODEL;
    const int N = z ? D_MODEL : D_FF;
    const int n0 = (z ? (bid & 15) : (bid & 63)) * 64;
    const int k0 = (z ? (bid >> 4) : (bid >> 6)) * 64;
    ttile(W, WT, K, N, n0, k0, f32, tile, threadIdx.x);
}

// MFMA GEMM: C bf16 = A[M,K] @ BT[N,K]^T (+bias)(+relu). 128x128 tile, 4 waves,
// BK=64, global_load_lds staging, XOR-swizzled unpadded LDS, XCD-chunked swizzle.
// NMAT>1: fused QKV; which==2 (V) writes V^T directly. SPLITK>1: kslice slabs.
template<bool RELU, bool BIAS, int NMAT, int SPLITK>
__global__ __launch_bounds__(256) void mgemm_kernel(const bf16* __restrict__ A,
    const bf16* __restrict__ BT, const void* __restrict__ bias,
    bf16* __restrict__ C, int M, int N, int K, const int* __restrict__ flagp)
{
    const bool inF32 = (*flagp) != 0;

    __shared__ unsigned short sA[128 * 64];   // 16 KB
    __shared__ unsigned short sB[128 * 64];   // 16 KB

    // XCD-chunked swizzle (bijective, nwg % 8 == 0)
    const int gx  = gridDim.x, gy = gridDim.y;
    const int nwg = gx * gy * gridDim.z;
    const int lin = blockIdx.x + gx * (blockIdx.y + gy * blockIdx.z);
    const int rid = (lin & 7) * (nwg >> 3) + (lin >> 3);
    const int by  = rid % gy;          // row tile (fastest -> B-panel reuse)
    const int tq  = rid / gy;
    const int bx  = tq % gx;
    const int bz  = tq / gx;

    int which = 0, colb = bx;
    if (NMAT > 1) { which = bx >> 3; colb = bx & 7; }
    const int kslice = (SPLITK > 1) ? bz : 0;
    const int Kspan  = K / SPLITK;
    const int kbase  = kslice * Kspan;
    const bf16* Bp = BT + (size_t)which * N * K;
    bf16*       Cp = C  + (size_t)which * M * N + (size_t)kslice * M * N;

    const int row0 = by * 128;
    const int col0 = colb * 128;

    const int t    = threadIdx.x;
    const int wave = t >> 6;
    const int lane = t & 63;
    const int lm   = lane & 15;
    const int q    = lane >> 4;
    const int wm   = (wave & 1) * 64;
    const int wn   = (wave >> 1) * 64;

    facc4 acc[4][4];
    #pragma unroll
    for (int i = 0; i < 4; ++i)
        #pragma unroll
        for (int j = 0; j < 4; ++j)
            acc[i][j] = (facc4){0.f, 0.f, 0.f, 0.f};

    for (int k0 = kbase; k0 < kbase + Kspan; k0 += 64) {
        __syncthreads();
        #pragma unroll
        for (int j = 0; j < 4; ++j) {
            const int ch = (wave * 4 + j) * 64 + lane;   // 0..1023
            const int r  = ch >> 3;
            const int cs = ch & 7;
            const int c  = cs ^ (r & 7);
            gld16(A  + (size_t)(row0 + r) * K + k0 + 8 * c, &sA[(wave * 4 + j) * 512]);
            gld16(Bp + (size_t)(col0 + r) * K + k0 + 8 * c, &sB[(wave * 4 + j) * 512]);
        }
        __syncthreads();

        #pragma unroll
        for (int kk = 0; kk < 64; kk += 32) {
            const int cr = (kk >> 3) + q;
            frag8 af[4], bfr[4];
            #pragma unroll
            for (int im = 0; im < 4; ++im) {
                const int m = wm + 16 * im + lm;
                af[im] = *reinterpret_cast<const frag8*>(&sA[m * 64 + ((cr ^ (m & 7)) << 3)]);
            }
            #pragma unroll
            for (int in = 0; in < 4; ++in) {
                const int n = wn + 16 * in + lm;
                bfr[in] = *reinterpret_cast<const frag8*>(&sB[n * 64 + ((cr ^ (n & 7)) << 3)]);
            }
            #pragma unroll
            for (int im = 0; im < 4; ++im)
                #pragma unroll
                for (int in = 0; in < 4; ++in)
                    acc[im][in] = __builtin_amdgcn_mfma_f32_16x16x32_bf16(af[im], bfr[in], acc[im][in], 0, 0, 0);
        }
    }

    if (NMAT > 1 && which == 2) {
        // V slot gets V^T directly: row = token (b*2048+s), col = h*64+d.
        #pragma unroll
        for (int in = 0; in < 4; ++in) {
            const int col = col0 + wn + 16*in + lm;     // 0..1023
            const int hh = col >> 6, dd = col & 63;
            #pragma unroll
            for (int im = 0; im < 4; ++im) {
                const int rowb = row0 + wm + 16*im + 4*q;   // +r
                const int bb = rowb >> 11, ss = rowb & 2047;
                union { uint2 v; unsigned u[2]; } ov;
                ov.u[0] = cvtpk_bf16(acc[im][in][0], acc[im][in][1]);
                ov.u[1] = cvtpk_bf16(acc[im][in][2], acc[im][in][3]);
                *reinterpret_cast<uint2*>(Cp + ((size_t)((bb * 16 + hh) * 64 + dd)) * 2048 + ss) = ov.v;
            }
        }
        return;
    }

    #pragma unroll
    for (int in = 0; in < 4; ++in) {
        const int col = col0 + wn + 16*in + lm;
        float bv = 0.f;
        if (BIAS && kslice == 0) bv = ld1(bias, col, inF32);
        #pragma unroll
        for (int im = 0; im < 4; ++im) {
            #pragma unroll
            for (int r = 0; r < 4; ++r) {
                const int row = row0 + wm + 16*im + 4*q + r;
                float v = acc[im][in][r] + bv;
                if (RELU) v = fmaxf(v, 0.f);
                Cp[(size_t)row * N + col] = __float2bfloat16(v);
            }
        }
    }
}

// 256x256 deep-pipelined MFMA GEMM (T3/T4): BK=64, 8 waves (2M x 4N, 512 thr),
// double-buffered 128 KB LDS (1 block/CU), 2-DEEP prefetch with COUNTED
// vmcnt(8) -- loads for tiles kt+1 and kt+2 stay in flight across barriers;
// no vmcnt(0) drain in steady state (raw s_barrier, not __syncthreads).
// Ordering proof: per-wave, each stage issues exactly 8 loads. At iteration
// tail, outstanding = prev-tile(8, oldest) + just-issued(8); vmcnt(8) retires
// the oldest 8 => buf[cur^1] fully landed before next compute. Writes into
// buf[cur] are issued only after lgkmcnt(0)+barrier closes all reads of it.
// Fragment/swizzle algebra identical to mgemm (proven). Requires K/64 >= 2.
template<bool RELU, bool BIAS>
__global__ __launch_bounds__(512, 2) void gemm256_kernel(const bf16* __restrict__ A,
    const bf16* __restrict__ BT, const void* __restrict__ bias,
    bf16* __restrict__ C, int M, int N, int K, const int* __restrict__ flagp)
{
    const bool inF32 = (*flagp) != 0;
    __shared__ __align__(16) unsigned short sA[2][256 * 64];   // 64 KB
    __shared__ __align__(16) unsigned short sB[2][256 * 64];   // 64 KB

    // XCD-chunked swizzle (nwg % 8 == 0), row-tile fastest
    const int gx = gridDim.x, gy = gridDim.y;
    const int nwg = gx * gy;
    const int lin = blockIdx.x + gx * blockIdx.y;
    const int rid = (lin & 7) * (nwg >> 3) + (lin >> 3);
    const int by = rid % gy;
    const int bx = rid / gy;

    const int row0 = by * 256;
    const int col0 = bx * 256;

    const int t    = threadIdx.x;   // 0..511
    const int wave = t >> 6;        // 0..7
    const int lane = t & 63;
    const int lm   = lane & 15;
    const int q    = lane >> 4;
    const int wm   = (wave >> 2) * 128;   // 2 M-groups
    const int wn   = (wave & 3) * 64;     // 4 N-groups

    const int NK = K >> 6;

    auto stage = [&](int bi, int kt) {
        const int k0 = kt << 6;
        #pragma unroll
        for (int j = 0; j < 4; ++j) {
            const int ch = j * 512 + t;          // 0..2047 = 256 rows x 8 chunks
            const int r  = ch >> 3;
            const int c  = (ch & 7) ^ (r & 7);   // XOR swizzle (same as mgemm)
            gld16(A  + (size_t)(row0 + r) * K + k0 + 8 * c, &sA[bi][ch * 8]);
            gld16(BT + (size_t)(col0 + r) * K + k0 + 8 * c, &sB[bi][ch * 8]);
        }
    };

    facc4 acc[8][4];
    #pragma unroll
    for (int i = 0; i < 8; ++i)
        #pragma unroll
        for (int j = 0; j < 4; ++j)
            acc[i][j] = (facc4){0.f, 0.f, 0.f, 0.f};

    // prologue: 2-deep prefetch; vmcnt(8) => tile 0's 8 loads landed
    stage(0, 0);
    stage(1, 1);
    asm volatile("s_waitcnt vmcnt(8)" ::: "memory");
    __builtin_amdgcn_s_barrier();

    for (int kt = 0; kt < NK; ++kt) {
        const int cur = kt & 1;

        __builtin_amdgcn_s_setprio(1);
        #pragma unroll
        for (int kk = 0; kk < 64; kk += 32) {
            const int cr = (kk >> 3) + q;
            frag8 af[8], bfr[4];
            #pragma unroll
            for (int im = 0; im < 8; ++im) {
                const int m = wm + 16 * im + lm;
                af[im] = *reinterpret_cast<const frag8*>(&sA[cur][m * 64 + ((cr ^ (m & 7)) << 3)]);
            }
            #pragma unroll
            for (int in = 0; in < 4; ++in) {
                const int n = wn + 16 * in + lm;
                bfr[in] = *reinterpret_cast<const frag8*>(&sB[cur][n * 64 + ((cr ^ (n & 7)) << 3)]);
            }
            #pragma unroll
            for (int im = 0; im < 8; ++im)
                #pragma unroll
                for (int in = 0; in < 4; ++in)
                    acc[im][in] = __builtin_amdgcn_mfma_f32_16x16x32_bf16(af[im], bfr[in], acc[im][in], 0, 0, 0);
        }
        __builtin_amdgcn_s_setprio(0);

        // close all reads of buf[cur] before re-staging it
        asm volatile("s_waitcnt lgkmcnt(0)" ::: "memory");
        __builtin_amdgcn_s_barrier();

        if (kt + 2 < NK) {
            stage(cur, kt + 2);
            asm volatile("s_waitcnt vmcnt(8)" ::: "memory");   // tile kt+1 landed
        } else {
            asm volatile("s_waitcnt vmcnt(0)" ::: "memory");   // tail: full drain
        }
        __builtin_amdgcn_s_barrier();   // buf[cur^1] ready for next iteration
    }

    #pragma unroll
    for (int in = 0; in < 4; ++in) {
        const int col = col0 + wn + 16*in + lm;
        float bv = 0.f;
        if (BIAS) bv = ld1(bias, col, inF32);
        #pragma unroll
        for (int im = 0; im < 8; ++im) {
            #pragma unroll
            for (int r = 0; r < 4; ++r) {
                const int row = row0 + wm + 16*im + 4*q + r;
                float v = acc[im][in][r] + bv;
                if (RELU) v = fmaxf(v, 0.f);
                C[(size_t)row * N + col] = __float2bfloat16(v);
            }
        }
    }
}

// MFMA flash attention v9 (unchanged from R8/R10): 128q block, 4 waves x 32q,
// KTILE=128, dbuf staging, XCD-chunked role swizzle, in-register P, permlane
// routing, cvt_pk packs, exp2-domain softmax + local-max defer, setprio.
__global__ __launch_bounds__(256, 2) void fattn_kernel(
    const bf16* __restrict__ Qg, const bf16* __restrict__ Kg,
    const bf16* __restrict__ VTg, const int* __restrict__ mask,
    bf16* __restrict__ ctx)
{
    __shared__ unsigned short sK[2][128 * 64];    // 2 x 16 KB, swizzled [kk][d]
    __shared__ unsigned short sV[2][64 * 128];    // 2 x 16 KB, swizzled [d][kk]
    __shared__ __align__(16) float madd[SEQ];     // 8 KB, log2-domain mask add

    const int t    = threadIdx.x;                 // 0..255
    const int lin  = blockIdx.x + 16 * (blockIdx.y + 16 * blockIdx.z);
    const int rid  = (lin & 7) * 64 + (lin >> 3);
    const int qt   = rid & 15;
    const int h    = (rid >> 4) & 15;
    const int b    = rid >> 8;
    const int q0   = qt * 128;
    const int bh   = b * N_HEADS + h;
    const int wave = t >> 6;                      // 0..3
    const int lane = t & 63;
    const int lm   = lane & 15;
    const int qd   = lane >> 4;
    const bool qo  = (qd & 1) != 0;

    const float SCL = 0.18033688011112042f;   // 0.125 * log2(e)

    auto stage = [&](int bi, int kt) {
        const int k0 = kt * KTILE;
        #pragma unroll
        for (int j = 0; j < 4; ++j) {
            const int ch = (wave * 4 + j) * 64 + lane;   // 0..1023
            const int rK = ch >> 3, cK = (ch & 7) ^ (rK & 7);
            gld16(Kg + ((size_t)(b * SEQ + k0 + rK)) * D_MODEL + h * DK + 8 * cK,
                  &sK[bi][(wave * 4 + j) * 512]);
            const int rV = ch >> 4, cV = (ch & 15) ^ (rV & 15);
            gld16(VTg + ((size_t)(bh * DK + rV)) * SEQ + k0 + 8 * cV,
                  &sV[bi][(wave * 4 + j) * 512]);
        }
    };

    stage(0, 0);
    #pragma unroll
    for (int i = 0; i < SEQ / (256 * 4); ++i) {
        const int idx = (i * 256 + t) * 4;
        const int4 mv = *reinterpret_cast<const int4*>(&mask[b * SEQ + idx]);
        madd[idx + 0] = (mv.x == 0) ? -1.442695e9f : 0.f;
        madd[idx + 1] = (mv.y == 0) ? -1.442695e9f : 0.f;
        madd[idx + 2] = (mv.z == 0) ? -1.442695e9f : 0.f;
        madd[idx + 3] = (mv.w == 0) ? -1.442695e9f : 0.f;
    }

    frag8 qf[2][2];
    #pragma unroll
    for (int s = 0; s < 2; ++s) {
        const bf16* qsrc = Qg + ((size_t)(b * SEQ + q0 + 32 * wave + 16 * s + lm)) * D_MODEL + h * DK;
        qf[s][0] = *reinterpret_cast<const frag8*>(qsrc + 8 * qd);
        qf[s][1] = *reinterpret_cast<const frag8*>(qsrc + 32 + 8 * qd);
    }

    facc4 accO[2][4];
    #pragma unroll
    for (int s = 0; s < 2; ++s)
        #pragma unroll
        for (int in = 0; in < 4; ++in) accO[s][in] = (facc4){0.f, 0.f, 0.f, 0.f};
    float m_r[2] = {-1e30f, -1e30f}, l_r[2] = {0.f, 0.f};

    for (int kt = 0; kt < SEQ / KTILE; ++kt) {
        const int cur = kt & 1;
        const int k0  = kt * KTILE;
        __syncthreads();
        if (kt + 1 < SEQ / KTILE) stage(cur ^ 1, kt + 1);

        facc4 accST[2][8];
        #pragma unroll
        for (int s = 0; s < 2; ++s)
            #pragma unroll
            for (int i = 0; i < 8; ++i) accST[s][i] = (facc4){0.f, 0.f, 0.f, 0.f};
        __builtin_amdgcn_s_setprio(1);
        #pragma unroll
        for (int i = 0; i < 8; ++i) {
            #pragma unroll
            for (int s2 = 0; s2 < 2; ++s2) {
                const int cr = 4 * s2 + qd;
                frag8 kf = *reinterpret_cast<const frag8*>(
                    &sK[cur][(16 * i + lm) * 64 + ((cr ^ (lm & 7)) << 3)]);
                accST[0][i] = __builtin_amdgcn_mfma_f32_16x16x32_bf16(kf, qf[0][s2], accST[0][i], 0, 0, 0);
                accST[1][i] = __builtin_amdgcn_mfma_f32_16x16x32_bf16(kf, qf[1][s2], accST[1][i], 0, 0, 0);
            }
        }
        __builtin_amdgcn_s_setprio(0);

        facc4 vmx[2];
        #pragma unroll
        for (int s = 0; s < 2; ++s) vmx[s] = (facc4){-1e30f, -1e30f, -1e30f, -1e30f};
        #pragma unroll
        for (int i = 0; i < 8; ++i) {
            const facc4 mv = *reinterpret_cast<const facc4*>(&madd[k0 + 16 * i + 4 * qd]);
            #pragma unroll
            for (int s = 0; s < 2; ++s) {
                #pragma unroll
                for (int r = 0; r < 4; ++r) {
                    accST[s][i][r] = fmaf(accST[s][i][r], SCL, mv[r]);
                    vmx[s][r] = fmaxf(vmx[s][r], accST[s][i][r]);
                }
            }
        }
        float mn[2], alpha[2] = {1.f, 1.f};
        bool resc[2];
        #pragma unroll
        for (int s = 0; s < 2; ++s) {
            const float mloc = fmaxf(fmaxf(vmx[s][0], vmx[s][1]), fmaxf(vmx[s][2], vmx[s][3]));
            const bool skip = __all(mloc - m_r[s] <= 11.54f) != 0;
            resc[s] = !skip;
            if (skip) {
                mn[s] = m_r[s];
            } else {
                float m0 = mloc;
                m0 = fmaxf(m0, __shfl_xor(m0, 16));
                m0 = fmaxf(m0, __shfl_xor(m0, 32));
                mn[s] = fmaxf(m_r[s], m0);
                alpha[s] = __builtin_amdgcn_exp2f(m_r[s] - mn[s]);
                m_r[s] = mn[s];
            }
        }

        unsigned up[2][8][2];
        facc4 ps4[2];
        #pragma unroll
        for (int s = 0; s < 2; ++s) ps4[s] = (facc4){0.f, 0.f, 0.f, 0.f};
        #pragma unroll
        for (int s = 0; s < 2; ++s) {
            #pragma unroll
            for (int i = 0; i < 8; ++i) {
                const float p0 = __builtin_amdgcn_exp2f(accST[s][i][0] - mn[s]);
                const float p1 = __builtin_amdgcn_exp2f(accST[s][i][1] - mn[s]);
                const float p2 = __builtin_amdgcn_exp2f(accST[s][i][2] - mn[s]);
                const float p3 = __builtin_amdgcn_exp2f(accST[s][i][3] - mn[s]);
                ps4[s][0] += p0; ps4[s][1] += p1; ps4[s][2] += p2; ps4[s][3] += p3;
                up[s][i][0] = cvtpk_bf16(p0, p1);
                up[s][i][1] = cvtpk_bf16(p2, p3);
            }
        }
        #pragma unroll
        for (int s = 0; s < 2; ++s) {
            float ps = (ps4[s][0] + ps4[s][1]) + (ps4[s][2] + ps4[s][3]);
            ps += __shfl_xor(ps, 16);
            ps += __shfl_xor(ps, 32);
            if (resc[s]) {
                l_r[s] = l_r[s] * alpha[s] + ps;
                #pragma unroll
                for (int in = 0; in < 4; ++in)
                    #pragma unroll
                    for (int r = 0; r < 4; ++r) accO[s][in][r] *= alpha[s];
            } else {
                l_r[s] += ps;
            }
        }

        __builtin_amdgcn_s_setprio(1);
        #pragma unroll
        for (int c = 0; c < 4; ++c) {
            union { frag8 f; unsigned u[4]; } pf0_, pf1_;
            #pragma unroll
            for (int s = 0; s < 2; ++s) {
                unsigned a0 = up[s][2*c][0],     a1 = up[s][2*c][1];
                unsigned b0 = up[s][2*c + 1][0], b1 = up[s][2*c + 1][1];
                asm("v_permlane32_swap_b32 %0, %1" : "+v"(a0), "+v"(b0));
                asm("v_permlane32_swap_b32 %0, %1" : "+v"(a1), "+v"(b1));
                const unsigned t0 = qo ? a0 : b0;
                const unsigned t1 = qo ? a1 : b1;
                const unsigned r0 = __shfl_xor(t0, 16);
                const unsigned r1 = __shfl_xor(t1, 16);
                unsigned u0 = qo ? r0 : a0;   // kk = 32c+8qd+0,1
                unsigned u1 = qo ? r1 : a1;   // kk = 32c+8qd+2,3
                unsigned u2 = qo ? b0 : r0;  // kk = 32c+8qd+4,5
                unsigned u3 = qo ? b1 : r1;  // kk = 32c+8qd+6,7
                if (s == 0) { pf0_.u[0]=u0; pf0_.u[1]=u1; pf0_.u[2]=u2; pf0_.u[3]=u3; }
                else        { pf1_.u[0]=u0; pf1_.u[1]=u1; pf1_.u[2]=u2; pf1_.u[3]=u3; }
            }
            #pragma unroll
            for (int in = 0; in < 4; ++in) {
                const int cr = 4 * c + qd;
                frag8 vf = *reinterpret_cast<const frag8*>(
                    &sV[cur][(16 * in + lm) * 128 + ((cr ^ lm) << 3)]);
                accO[0][in] = __builtin_amdgcn_mfma_f32_16x16x32_bf16(vf, pf0_.f, accO[0][in], 0, 0, 0);
                accO[1][in] = __builtin_amdgcn_mfma_f32_16x16x32_bf16(vf, pf1_.f, accO[1][in], 0, 0, 0);
            }
        }
        __builtin_amdgcn_s_setprio(0);
    }

    #pragma unroll
    for (int s = 0; s < 2; ++s) {
        const float invl = 1.f / l_r[s];
        bf16* crow = ctx + ((size_t)(b * SEQ + q0 + 32 * wave + 16 * s + lm)) * D_MODEL + h * DK;
        #pragma unroll
        for (int in = 0; in < 4; ++in) {
            union { uint2 v; unsigned u[2]; } ov;
            ov.u[0] = cvtpk_bf16(accO[s][in][0] * invl, accO[s][in][1] * invl);
            ov.u[1] = cvtpk_bf16(accO[s][in][2] * invl, accO[s][in][3] * invl);
            *reinterpret_cast<uint2*>(crow + 16 * in + 4 * qd) = ov.v;
        }
    }
}

// LayerNorm v3 (G13): 128 threads/row, row register-resident, wave shfl reduce
// + 2-entry LDS combine, cvt_pk packed stores. ddof=1.
template<bool BASE_WS, bool OUT_WS>
__global__ __launch_bounds__(128) void ln_kernel(const void* __restrict__ base,
    const bf16* __restrict__ addv, const bf16* __restrict__ addv2,
    const void* __restrict__ alpha, const void* __restrict__ bias,
    void* __restrict__ outp, const int* __restrict__ flagp)
{
    const bool inF32 = (*flagp) != 0;
    __shared__ float red[2];
    __shared__ float red2[2];
    const int row = blockIdx.x, t = threadIdx.x;
    const size_t off = (size_t)row * D_MODEL + t * 8;

    float v[8];
    {
        const U8 bz = ld8bf(base, off, BASE_WS ? false : inF32);
        uint4 a1 = *reinterpret_cast<const uint4*>(addv + off);
        const unsigned short* a1s = reinterpret_cast<const unsigned short*>(&a1);
        #pragma unroll
        for (int j = 0; j < 8; ++j) v[j] = bf2f(bz.v[j]) + bf2f(a1s[j]);
        if (addv2) {
            uint4 a2 = *reinterpret_cast<const uint4*>(addv2 + off);
            const unsigned short* a2s = reinterpret_cast<const unsigned short*>(&a2);
            #pragma unroll
            for (int j = 0; j < 8; ++j) v[j] += bf2f(a2s[j]);
        }
    }

    float s = ((v[0]+v[1]) + (v[2]+v[3])) + ((v[4]+v[5]) + (v[6]+v[7]));
    #pragma unroll
    for (int o = 1; o < 64; o <<= 1) s += __shfl_xor(s, o);
    if ((t & 63) == 0) red[t >> 6] = s;
    __syncthreads();
    const float mean = (red[0] + red[1]) * (1.f / (float)D_MODEL);

    float sq = 0.f;
    #pragma unroll
    for (int j = 0; j < 8; ++j) { const float d = v[j] - mean; sq += d * d; }
    #pragma unroll
    for (int o = 1; o < 64; o <<= 1) sq += __shfl_xor(sq, o);
    if ((t & 63) == 0) red2[t >> 6] = sq;
    __syncthreads();
    const float var = (red2[0] + red2[1]) * (1.f / (float)(D_MODEL - 1));
    const float inv = 1.f / (sqrtf(var) + LN_EPS);

    float av[8], bv[8];
    ld8f(alpha, t * 8, inF32, av);
    ld8f(bias,  t * 8, inF32, bv);
    float y[8];
    #pragma unroll
    for (int j = 0; j < 8; ++j)
        y[j] = av[j] * (v[j] - mean) * inv + bv[j];

    if (OUT_WS || !inF32) {
        union { uint4 u; unsigned w[4]; } o_;
        o_.w[0] = cvtpk_bf16(y[0], y[1]);
        o_.w[1] = cvtpk_bf16(y[2], y[3]);
        o_.w[2] = cvtpk_bf16(y[4], y[5]);
        o_.w[3] = cvtpk_bf16(y[6], y[7]);
        *reinterpret_cast<uint4*>((bf16*)outp + off) = o_.u;
    } else {
        float* op = (float*)outp + off;
        const float4 f0 = {y[0], y[1], y[2], y[3]};
        const float4 f1 = {y[4], y[5], y[6], y[7]};
        *reinterpret_cast<float4*>(op)     = f0;
        *reinterpret_cast<float4*>(op + 4) = f1;
    }
}

extern "C" void kernel_launch(void* const* d_in, const int* in_sizes, int n_in,
                              void* d_out, int out_size, void* d_ws, size_t ws_size,
                              hipStream_t stream)
{
    const void* x    = d_in[0];
    const int*  mask = (const int*)d_in[1];
    const void* wq   = d_in[2];
    const void* wk   = d_in[3];
    const void* wv   = d_in[4];
    const void* wo   = d_in[5];
    const void* wo_b = d_in[6];
    const void* w1   = d_in[7];
    const void* b1   = d_in[8];
    const void* w2   = d_in[9];
    const void* b2   = d_in[10];
    const void* al1  = d_in[11];
    const void* bi1  = d_in[12];
    const void* al2  = d_in[13];
    const void* bi2  = d_in[14];

    const size_t MB = 1024 * 1024;
    char* ws = (char*)d_ws;
    const bool BIG = ws_size >= 64 * MB + 4096;     // R8 confirmed this branch runs
    if (!BIG && ws_size < 56 * MB + 4096) return;   // loud fail: out stays 0

    if (BIG) {
        // 64 MB plan. QKV writes Q[0,8) K[8,16) and V^T DIRECTLY into [16,24).
        bf16* Qb   = (bf16*)(ws + 0 * MB);
        bf16* Kb   = (bf16*)(ws + 8 * MB);
        bf16* VTb  = (bf16*)(ws + 16 * MB);
        bf16* Xb   = (bf16*)(ws + 24 * MB);
        bf16* WT4  = (bf16*)(ws + 32 * MB);
        bf16* WOT  = WT4 + (size_t)3 * D_MODEL * D_MODEL;
        bf16* W1T  = (bf16*)(ws + 40 * MB);
        bf16* W2T  = (bf16*)(ws + 48 * MB);
        bf16* CTXb = (bf16*)(ws + 56 * MB);
        bf16* ATT0 = (bf16*)(ws + 0 * MB);
        bf16* ATT1 = (bf16*)(ws + 8 * MB);
        bf16* X1b  = (bf16*)(ws + 56 * MB);
        bf16* FFb  = (bf16*)(ws + 0 * MB);
        bf16* X20  = (bf16*)(ws + 32 * MB);
        bf16* X21  = (bf16*)(ws + 40 * MB);
        int*  flagp = (int*)(ws + 64 * MB);

        probe_kernel<<<1, 256, 0, stream>>>(x, flagp);
        prep_kernel<<<dim3(5120), 256, 0, stream>>>(x, Xb, wq, wk, wv, wo, WT4,
                                                    w1, w2, W1T, W2T, flagp);

        mgemm_kernel<false, false, 3, 1><<<dim3(24, 32), 256, 0, stream>>>(
            Xb, WT4, nullptr, Qb, ROWS, D_MODEL, D_MODEL, flagp);

        fattn_kernel<<<dim3(SEQ / 128, N_HEADS, BATCH), 256, 0, stream>>>(Qb, Kb, VTb, mask, CTXb);

        mgemm_kernel<false, true, 1, 2><<<dim3(8, 32, 2), 256, 0, stream>>>(
            CTXb, WOT, wo_b, ATT0, ROWS, D_MODEL, D_MODEL, flagp);
        ln_kernel<false, true><<<ROWS, 128, 0, stream>>>(x, ATT0, ATT1, al1, bi1, X1b, flagp);

        gemm256_kernel<true, true><<<dim3(16, 16), 512, 0, stream>>>(
            X1b, W1T, b1, FFb, ROWS, D_FF, D_MODEL, flagp);

        mgemm_kernel<false, true, 1, 2><<<dim3(8, 32, 2), 256, 0, stream>>>(
            FFb, W2T, b2, X20, ROWS, D_MODEL, D_FF, flagp);
        ln_kernel<true, false><<<ROWS, 128, 0, stream>>>(X1b, X20, X21, al2, bi2, d_out, flagp);
    } else {
        // 56 MB fallback (no split-K). QKV writes V^T directly into [16,24).
        bf16* Qb    = (bf16*)(ws + 0 * MB);
        bf16* Kb    = (bf16*)(ws + 8 * MB);
        bf16* VTb   = (bf16*)(ws + 16 * MB);
        bf16* Xb    = (bf16*)(ws + 24 * MB);
        bf16* WQKVT = (bf16*)(ws + 32 * MB);
        bf16* CTXb  = (bf16*)(ws + 32 * MB);
        bf16* W2T   = (bf16*)(ws + 32 * MB);
        bf16* WOT   = (bf16*)(ws + 0 * MB);
        bf16* ATT0  = (bf16*)(ws + 48 * MB);
        bf16* W1T   = (bf16*)(ws + 48 * MB);
        bf16* X20   = (bf16*)(ws + 48 * MB);
        bf16* X1b   = (bf16*)(ws + 40 * MB);
        bf16* FFb   = (bf16*)(ws + 0 * MB);
        int*  flagp = (int*)(ws + 56 * MB);

        probe_kernel<<<1, 256, 0, stream>>>(x, flagp);
        xcvt_kernel<<<dim3(ROWS * D_MODEL / 2048), 256, 0, stream>>>(x, Xb, flagp);

        transpose_kernel<<<dim3(16, 16), 256, 0, stream>>>(wq, WQKVT,           D_MODEL, D_MODEL, flagp);
        transpose_kernel<<<dim3(16, 16), 256, 0, stream>>>(wk, WQKVT + 1048576, D_MODEL, D_MODEL, flagp);
        transpose_kernel<<<dim3(16, 16), 256, 0, stream>>>(wv, WQKVT + 2097152, D_MODEL, D_MODEL, flagp);

        mgemm_kernel<false, false, 3, 1><<<dim3(24, 32), 256, 0, stream>>>(
            Xb, WQKVT, nullptr, Qb, ROWS, D_MODEL, D_MODEL, flagp);

        fattn_kernel<<<dim3(SEQ / 128, N_HEADS, BATCH), 256, 0, stream>>>(Qb, Kb, VTb, mask, CTXb);

        transpose_kernel<<<dim3(16, 16), 256, 0, stream>>>(wo, WOT, D_MODEL, D_MODEL, flagp);
        mgemm_kernel<false, true, 1, 1><<<dim3(8, 32), 256, 0, stream>>>(
            CTXb, WOT, wo_b, ATT0, ROWS, D_MODEL, D_MODEL, flagp);
        ln_kernel<false, true><<<ROWS, 128, 0, stream>>>(x, ATT0, nullptr, al1, bi1, X1b, flagp);

        transpose_kernel<<<dim3(64, 16), 256, 0, stream>>>(w1, W1T, D_MODEL, D_FF, flagp);
        gemm256_kernel<true, true><<<dim3(16, 16), 512, 0, stream>>>(
            X1b, W1T, b1, FFb, ROWS, D_FF, D_MODEL, flagp);

        transpose_kernel<<<dim3(16, 64), 256, 0, stream>>>(w2, W2T, D_FF, D_MODEL, flagp);
        mgemm_kernel<false, true, 1, 1><<<dim3(8, 32), 256, 0, stream>>>(
            FFb, W2T, b2, X20, ROWS, D_MODEL, D_FF, flagp);
        ln_kernel<true, false><<<ROWS, 128, 0, stream>>>(X1b, X20, nullptr, al2, bi2, d_out, flagp);
    }
}

// Round 12
// 348.138 us; speedup vs baseline: 1.0440x; 1.0242x over previous
//
#include <hip/hip_runtime.h>
#include <hip/hip_bf16.h>

#define D_MODEL 1024
#define N_HEADS 16
#define DK      64
#define SEQ     2048
#define BATCH   2
#define D_FF    4096
#define ROWS    (BATCH*SEQ)   // 4096
#define LN_EPS  1e-6f
#define KTILE   128           // fattn K-tile

typedef __hip_bfloat16 bf16;
typedef __attribute__((ext_vector_type(8))) short frag8;   // 8 bf16 (MFMA A/B)
typedef __attribute__((ext_vector_type(4))) float facc4;   // 4 f32 (MFMA C/D)

__device__ inline float bf2f(unsigned short u){ return __uint_as_float(((unsigned)u) << 16); }
__device__ inline float toF(bf16 v){ return __bfloat162float(v); }
__device__ inline unsigned short f2bu(float f){ bf16 h = __float2bfloat16(f); return *reinterpret_cast<unsigned short*>(&h); }

// 2 f32 -> packed 2x bf16 (RNE), single instruction on gfx950.
__device__ inline unsigned cvtpk_bf16(float lo, float hi){
    unsigned r;
    asm("v_cvt_pk_bf16_f32 %0, %1, %2" : "=v"(r) : "v"(lo), "v"(hi));
    return r;
}

__device__ inline float ld1(const void* p, size_t idx, bool f32) {
    return f32 ? ((const float*)p)[idx] : toF(((const bf16*)p)[idx]);
}

struct U8 { unsigned short v[8]; };
__device__ inline U8 ld8bf(const void* p, size_t idx, bool f32) {
    U8 r;
    if (!f32) {
        *reinterpret_cast<uint4*>(r.v) = *reinterpret_cast<const uint4*>((const unsigned short*)p + idx);
    } else {
        const float* f = (const float*)p + idx;
        const float4 a = *reinterpret_cast<const float4*>(f);
        const float4 b = *reinterpret_cast<const float4*>(f + 4);
        r.v[0]=f2bu(a.x); r.v[1]=f2bu(a.y); r.v[2]=f2bu(a.z); r.v[3]=f2bu(a.w);
        r.v[4]=f2bu(b.x); r.v[5]=f2bu(b.y); r.v[6]=f2bu(b.z); r.v[7]=f2bu(b.w);
    }
    return r;
}

// 8 f32 values from alpha/bias-style vectors, dtype-aware, vectorized (G13).
__device__ inline void ld8f(const void* p, int idx, bool f32, float* o) {
    if (!f32) {
        uint4 u = *reinterpret_cast<const uint4*>((const unsigned short*)p + idx);
        const unsigned short* us = reinterpret_cast<const unsigned short*>(&u);
        #pragma unroll
        for (int j = 0; j < 8; ++j) o[j] = bf2f(us[j]);
    } else {
        const float* f = (const float*)p + idx;
        const float4 a = *reinterpret_cast<const float4*>(f);
        const float4 b = *reinterpret_cast<const float4*>(f + 4);
        o[0]=a.x; o[1]=a.y; o[2]=a.z; o[3]=a.w;
        o[4]=b.x; o[5]=b.y; o[6]=b.z; o[7]=b.w;
    }
}

// Async global->LDS, 16B/lane. LDS dst is wave-uniform base; lane i -> dst+i*16B.
__device__ inline void gld16(const void* g, void* l) {
    __builtin_amdgcn_global_load_lds(
        reinterpret_cast<const __attribute__((address_space(1))) void*>(
            reinterpret_cast<uintptr_t>(g)),
        reinterpret_cast<__attribute__((address_space(3))) void*>(
            (unsigned int)reinterpret_cast<uintptr_t>(l)),
        16, 0, 0);
}

// Dtype probe: fp32 bits misread as bf16 give Inf/NaN/huge values.
__global__ void probe_kernel(const void* __restrict__ xp, int* __restrict__ flag) {
    __shared__ int hit;
    if (threadIdx.x == 0) hit = 0;
    __syncthreads();
    const bf16* p = (const bf16*)xp;
    int bad = 0;
    for (int i = threadIdx.x; i < 8192; i += 256) {
        float v = fabsf(toF(p[i]));
        if (!(v <= 1e5f)) bad = 1;
    }
    if (bad) atomicOr(&hit, 1);
    __syncthreads();
    if (threadIdx.x == 0) *flag = hit;   // 1 => inputs are fp32
}

// x (flag dtype) -> canonical bf16 ws buffer. 8 elems/thread.
__global__ __launch_bounds__(256) void xcvt_kernel(const void* __restrict__ x,
    bf16* __restrict__ out, const int* __restrict__ flagp)
{
    const bool f32 = (*flagp) != 0;
    const size_t i = ((size_t)blockIdx.x * 256 + threadIdx.x) * 8;
    U8 d = ld8bf(x, i, f32);
    *reinterpret_cast<uint4*>(out + i) = *reinterpret_cast<const uint4*>(d.v);
}

// Shared 64x64 transpose tile body: W[k0+.., n0+..] -> WT[n0+..][k0+..].
__device__ inline void ttile(const void* W, bf16* WT, int K, int N,
                             int n0, int k0, bool f32, float (*tile)[65], int t)
{
    const int lr = t >> 2;          // 0..63
    const int lc = (t & 3) * 16;    // {0,16,32,48}
    if (!f32) {
        const unsigned short* src = (const unsigned short*)W + (size_t)(k0 + lr) * N + n0 + lc;
        uint4 u0 = *reinterpret_cast<const uint4*>(src);
        uint4 u1 = *reinterpret_cast<const uint4*>(src + 8);
        const unsigned short* us0 = reinterpret_cast<const unsigned short*>(&u0);
        const unsigned short* us1 = reinterpret_cast<const unsigned short*>(&u1);
        #pragma unroll
        for (int j = 0; j < 8; ++j) {
            tile[lr][lc + j]     = bf2f(us0[j]);
            tile[lr][lc + 8 + j] = bf2f(us1[j]);
        }
    } else {
        const float* src = (const float*)W + (size_t)(k0 + lr) * N + n0 + lc;
        #pragma unroll
        for (int q4 = 0; q4 < 4; ++q4) {
            const float4 f = *reinterpret_cast<const float4*>(src + 4 * q4);
            tile[lr][lc + 4*q4 + 0] = f.x;
            tile[lr][lc + 4*q4 + 1] = f.y;
            tile[lr][lc + 4*q4 + 2] = f.z;
            tile[lr][lc + 4*q4 + 3] = f.w;
        }
    }
    __syncthreads();
    unsigned short o[16];
    #pragma unroll
    for (int j = 0; j < 16; ++j) o[j] = f2bu(tile[lc + j][lr]);
    bf16* dst = WT + (size_t)(n0 + lr) * K + k0 + lc;
    *reinterpret_cast<uint4*>(dst)     = *reinterpret_cast<const uint4*>(&o[0]);
    *reinterpret_cast<uint4*>(dst + 8) = *reinterpret_cast<const uint4*>(&o[8]);
}

// WT[n][k] = W[k][n], bf16 out. grid (N/64, K/64), 256 threads.
__global__ __launch_bounds__(256) void transpose_kernel(const void* __restrict__ W,
    bf16* __restrict__ WT, int K, int N, const int* __restrict__ flagp)
{
    __shared__ float tile[64][65];
    ttile(W, WT, K, N, blockIdx.x * 64, blockIdx.y * 64, (*flagp) != 0, tile, threadIdx.x);
}

// Merged prep: [0,2048) xcvt x->Xb; [2048,3072) transpose wq/wk/wv/wo -> WT4;
// [3072,5120) transpose w1 -> W1T, w2 -> W2T. One dispatch, 5120 blocks.
__global__ __launch_bounds__(256) void prep_kernel(
    const void* __restrict__ x, bf16* __restrict__ Xb,
    const void* __restrict__ wq, const void* __restrict__ wk,
    const void* __restrict__ wv, const void* __restrict__ wo, bf16* __restrict__ WT4,
    const void* __restrict__ w1, const void* __restrict__ w2,
    bf16* __restrict__ W1T, bf16* __restrict__ W2T,
    const int* __restrict__ flagp)
{
    __shared__ float tile[64][65];
    const bool f32 = (*flagp) != 0;
    const int id = blockIdx.x;
    if (id < 2048) {
        const size_t i = ((size_t)id * 256 + threadIdx.x) * 8;
        U8 d = ld8bf(x, i, f32);
        *reinterpret_cast<uint4*>(Xb + i) = *reinterpret_cast<const uint4*>(d.v);
        return;
    }
    if (id < 3072) {
        const int local = id - 2048;
        const int which = local >> 8;
        const void* W = (which == 0) ? wq : (which == 1) ? wk : (which == 2) ? wv : wo;
        bf16* WT = WT4 + (size_t)which * D_MODEL * D_MODEL;
        const int rem = local & 255;
        ttile(W, WT, D_MODEL, D_MODEL, (rem & 15) * 64, (rem >> 4) * 64, f32, tile, threadIdx.x);
        return;
    }
    const int local = id - 3072;
    const int z = local >> 10, bid = local & 1023;
    const void* W = z ? w2 : w1;
    bf16* WT = z ? W2T : W1T;
    const int K = z ? D_FF : D_MODEL;
    const int N = z ? D_MODEL : D_FF;
    const int n0 = (z ? (bid & 15) : (bid & 63)) * 64;
    const int k0 = (z ? (bid >> 4) : (bid >> 6)) * 64;
    ttile(W, WT, K, N, n0, k0, f32, tile, threadIdx.x);
}

// MFMA GEMM: C bf16 = A[M,K] @ BT[N,K]^T (+bias)(+relu). 128x128 tile, 4 waves,
// BK=64, global_load_lds staging, XOR-swizzled unpadded LDS, XCD-chunked swizzle.
// SPLITK>1: kslice slabs. (QKV now runs on gemm256.)
template<bool RELU, bool BIAS, int NMAT, int SPLITK>
__global__ __launch_bounds__(256) void mgemm_kernel(const bf16* __restrict__ A,
    const bf16* __restrict__ BT, const void* __restrict__ bias,
    bf16* __restrict__ C, int M, int N, int K, const int* __restrict__ flagp)
{
    const bool inF32 = (*flagp) != 0;

    __shared__ unsigned short sA[128 * 64];   // 16 KB
    __shared__ unsigned short sB[128 * 64];   // 16 KB

    // XCD-chunked swizzle (bijective, nwg % 8 == 0)
    const int gx  = gridDim.x, gy = gridDim.y;
    const int nwg = gx * gy * gridDim.z;
    const int lin = blockIdx.x + gx * (blockIdx.y + gy * blockIdx.z);
    const int rid = (lin & 7) * (nwg >> 3) + (lin >> 3);
    const int by  = rid % gy;          // row tile (fastest -> B-panel reuse)
    const int tq  = rid / gy;
    const int bx  = tq % gx;
    const int bz  = tq / gx;

    int which = 0, colb = bx;
    if (NMAT > 1) { which = bx >> 3; colb = bx & 7; }
    const int kslice = (SPLITK > 1) ? bz : 0;
    const int Kspan  = K / SPLITK;
    const int kbase  = kslice * Kspan;
    const bf16* Bp = BT + (size_t)which * N * K;
    bf16*       Cp = C  + (size_t)which * M * N + (size_t)kslice * M * N;

    const int row0 = by * 128;
    const int col0 = colb * 128;

    const int t    = threadIdx.x;
    const int wave = t >> 6;
    const int lane = t & 63;
    const int lm   = lane & 15;
    const int q    = lane >> 4;
    const int wm   = (wave & 1) * 64;
    const int wn   = (wave >> 1) * 64;

    facc4 acc[4][4];
    #pragma unroll
    for (int i = 0; i < 4; ++i)
        #pragma unroll
        for (int j = 0; j < 4; ++j)
            acc[i][j] = (facc4){0.f, 0.f, 0.f, 0.f};

    for (int k0 = kbase; k0 < kbase + Kspan; k0 += 64) {
        __syncthreads();
        #pragma unroll
        for (int j = 0; j < 4; ++j) {
            const int ch = (wave * 4 + j) * 64 + lane;   // 0..1023
            const int r  = ch >> 3;
            const int cs = ch & 7;
            const int c  = cs ^ (r & 7);
            gld16(A  + (size_t)(row0 + r) * K + k0 + 8 * c, &sA[(wave * 4 + j) * 512]);
            gld16(Bp + (size_t)(col0 + r) * K + k0 + 8 * c, &sB[(wave * 4 + j) * 512]);
        }
        __syncthreads();

        #pragma unroll
        for (int kk = 0; kk < 64; kk += 32) {
            const int cr = (kk >> 3) + q;
            frag8 af[4], bfr[4];
            #pragma unroll
            for (int im = 0; im < 4; ++im) {
                const int m = wm + 16 * im + lm;
                af[im] = *reinterpret_cast<const frag8*>(&sA[m * 64 + ((cr ^ (m & 7)) << 3)]);
            }
            #pragma unroll
            for (int in = 0; in < 4; ++in) {
                const int n = wn + 16 * in + lm;
                bfr[in] = *reinterpret_cast<const frag8*>(&sB[n * 64 + ((cr ^ (n & 7)) << 3)]);
            }
            #pragma unroll
            for (int im = 0; im < 4; ++im)
                #pragma unroll
                for (int in = 0; in < 4; ++in)
                    acc[im][in] = __builtin_amdgcn_mfma_f32_16x16x32_bf16(af[im], bfr[in], acc[im][in], 0, 0, 0);
        }
    }

    #pragma unroll
    for (int in = 0; in < 4; ++in) {
        const int col = col0 + wn + 16*in + lm;
        float bv = 0.f;
        if (BIAS && kslice == 0) bv = ld1(bias, col, inF32);
        #pragma unroll
        for (int im = 0; im < 4; ++im) {
            #pragma unroll
            for (int r = 0; r < 4; ++r) {
                const int row = row0 + wm + 16*im + 4*q + r;
                float v = acc[im][in][r] + bv;
                if (RELU) v = fmaxf(v, 0.f);
                Cp[(size_t)row * N + col] = __float2bfloat16(v);
            }
        }
    }
}

// 256x256 deep-pipelined MFMA GEMM (T3/T4, validated R11): BK=64, 8 waves
// (2M x 4N, 512 thr), double-buffered 128 KB LDS (1 block/CU), 2-DEEP prefetch
// with COUNTED vmcnt(8); raw s_barrier, no vmcnt(0) drain in steady state.
// NMAT>1: fused QKV (N=1024/mat; grid x = NMAT*4 col tiles); which==2 (V)
// writes V^T directly (index algebra copied from mgemm, tile-size-independent).
// Requires K/64 >= 2 and nwg % 8 == 0.
template<bool RELU, bool BIAS, int NMAT>
__global__ __launch_bounds__(512, 2) void gemm256_kernel(const bf16* __restrict__ A,
    const bf16* __restrict__ BT, const void* __restrict__ bias,
    bf16* __restrict__ C, int M, int N, int K, const int* __restrict__ flagp)
{
    const bool inF32 = (*flagp) != 0;
    __shared__ __align__(16) unsigned short sA[2][256 * 64];   // 64 KB
    __shared__ __align__(16) unsigned short sB[2][256 * 64];   // 64 KB

    // XCD-chunked swizzle (nwg % 8 == 0), row-tile fastest
    const int gx = gridDim.x, gy = gridDim.y;
    const int nwg = gx * gy;
    const int lin = blockIdx.x + gx * blockIdx.y;
    const int rid = (lin & 7) * (nwg >> 3) + (lin >> 3);
    const int by = rid % gy;
    const int bx = rid / gy;

    int which = 0, colb = bx;
    if (NMAT > 1) { which = bx >> 2; colb = bx & 3; }   // 4 col tiles per matrix
    const bf16* Bp = BT + (size_t)which * N * K;
    bf16*       Cp = C  + (size_t)which * M * N;

    const int row0 = by * 256;
    const int col0 = colb * 256;

    const int t    = threadIdx.x;   // 0..511
    const int wave = t >> 6;        // 0..7
    const int lane = t & 63;
    const int lm   = lane & 15;
    const int q    = lane >> 4;
    const int wm   = (wave >> 2) * 128;   // 2 M-groups
    const int wn   = (wave & 3) * 64;     // 4 N-groups

    const int NK = K >> 6;

    auto stage = [&](int bi, int kt) {
        const int k0 = kt << 6;
        #pragma unroll
        for (int j = 0; j < 4; ++j) {
            const int ch = j * 512 + t;          // 0..2047 = 256 rows x 8 chunks
            const int r  = ch >> 3;
            const int c  = (ch & 7) ^ (r & 7);   // XOR swizzle (same as mgemm)
            gld16(A  + (size_t)(row0 + r) * K + k0 + 8 * c, &sA[bi][ch * 8]);
            gld16(Bp + (size_t)(col0 + r) * K + k0 + 8 * c, &sB[bi][ch * 8]);
        }
    };

    facc4 acc[8][4];
    #pragma unroll
    for (int i = 0; i < 8; ++i)
        #pragma unroll
        for (int j = 0; j < 4; ++j)
            acc[i][j] = (facc4){0.f, 0.f, 0.f, 0.f};

    // prologue: 2-deep prefetch; vmcnt(8) => tile 0's 8 loads landed
    stage(0, 0);
    stage(1, 1);
    asm volatile("s_waitcnt vmcnt(8)" ::: "memory");
    __builtin_amdgcn_s_barrier();

    for (int kt = 0; kt < NK; ++kt) {
        const int cur = kt & 1;

        __builtin_amdgcn_s_setprio(1);
        #pragma unroll
        for (int kk = 0; kk < 64; kk += 32) {
            const int cr = (kk >> 3) + q;
            frag8 af[8], bfr[4];
            #pragma unroll
            for (int im = 0; im < 8; ++im) {
                const int m = wm + 16 * im + lm;
                af[im] = *reinterpret_cast<const frag8*>(&sA[cur][m * 64 + ((cr ^ (m & 7)) << 3)]);
            }
            #pragma unroll
            for (int in = 0; in < 4; ++in) {
                const int n = wn + 16 * in + lm;
                bfr[in] = *reinterpret_cast<const frag8*>(&sB[cur][n * 64 + ((cr ^ (n & 7)) << 3)]);
            }
            #pragma unroll
            for (int im = 0; im < 8; ++im)
                #pragma unroll
                for (int in = 0; in < 4; ++in)
                    acc[im][in] = __builtin_amdgcn_mfma_f32_16x16x32_bf16(af[im], bfr[in], acc[im][in], 0, 0, 0);
        }
        __builtin_amdgcn_s_setprio(0);

        // close all reads of buf[cur] before re-staging it
        asm volatile("s_waitcnt lgkmcnt(0)" ::: "memory");
        __builtin_amdgcn_s_barrier();

        if (kt + 2 < NK) {
            stage(cur, kt + 2);
            asm volatile("s_waitcnt vmcnt(8)" ::: "memory");   // tile kt+1 landed
        } else {
            asm volatile("s_waitcnt vmcnt(0)" ::: "memory");   // tail: full drain
        }
        __builtin_amdgcn_s_barrier();   // buf[cur^1] ready for next iteration
    }

    if (NMAT > 1 && which == 2) {
        // V slot gets V^T directly: row = token (b*2048+s), col = h*64+d.
        #pragma unroll
        for (int in = 0; in < 4; ++in) {
            const int col = col0 + wn + 16*in + lm;     // 0..1023
            const int hh = col >> 6, dd = col & 63;
            #pragma unroll
            for (int im = 0; im < 8; ++im) {
                const int rowb = row0 + wm + 16*im + 4*q;   // +r
                const int bb = rowb >> 11, ss = rowb & 2047;
                union { uint2 v; unsigned u[2]; } ov;
                ov.u[0] = cvtpk_bf16(acc[im][in][0], acc[im][in][1]);
                ov.u[1] = cvtpk_bf16(acc[im][in][2], acc[im][in][3]);
                *reinterpret_cast<uint2*>(Cp + ((size_t)((bb * 16 + hh) * 64 + dd)) * 2048 + ss) = ov.v;
            }
        }
        return;
    }

    #pragma unroll
    for (int in = 0; in < 4; ++in) {
        const int col = col0 + wn + 16*in + lm;
        float bv = 0.f;
        if (BIAS) bv = ld1(bias, col, inF32);
        #pragma unroll
        for (int im = 0; im < 8; ++im) {
            #pragma unroll
            for (int r = 0; r < 4; ++r) {
                const int row = row0 + wm + 16*im + 4*q + r;
                float v = acc[im][in][r] + bv;
                if (RELU) v = fmaxf(v, 0.f);
                Cp[(size_t)row * N + col] = __float2bfloat16(v);
            }
        }
    }
}

// MFMA flash attention v9 (unchanged): 128q block, 4 waves x 32q, KTILE=128,
// dbuf staging, XCD-chunked role swizzle, in-register P, permlane routing,
// cvt_pk packs, exp2-domain softmax + local-max defer, setprio.
__global__ __launch_bounds__(256, 2) void fattn_kernel(
    const bf16* __restrict__ Qg, const bf16* __restrict__ Kg,
    const bf16* __restrict__ VTg, const int* __restrict__ mask,
    bf16* __restrict__ ctx)
{
    __shared__ unsigned short sK[2][128 * 64];    // 2 x 16 KB, swizzled [kk][d]
    __shared__ unsigned short sV[2][64 * 128];    // 2 x 16 KB, swizzled [d][kk]
    __shared__ __align__(16) float madd[SEQ];     // 8 KB, log2-domain mask add

    const int t    = threadIdx.x;                 // 0..255
    const int lin  = blockIdx.x + 16 * (blockIdx.y + 16 * blockIdx.z);
    const int rid  = (lin & 7) * 64 + (lin >> 3);
    const int qt   = rid & 15;
    const int h    = (rid >> 4) & 15;
    const int b    = rid >> 8;
    const int q0   = qt * 128;
    const int bh   = b * N_HEADS + h;
    const int wave = t >> 6;                      // 0..3
    const int lane = t & 63;
    const int lm   = lane & 15;
    const int qd   = lane >> 4;
    const bool qo  = (qd & 1) != 0;

    const float SCL = 0.18033688011112042f;   // 0.125 * log2(e)

    auto stage = [&](int bi, int kt) {
        const int k0 = kt * KTILE;
        #pragma unroll
        for (int j = 0; j < 4; ++j) {
            const int ch = (wave * 4 + j) * 64 + lane;   // 0..1023
            const int rK = ch >> 3, cK = (ch & 7) ^ (rK & 7);
            gld16(Kg + ((size_t)(b * SEQ + k0 + rK)) * D_MODEL + h * DK + 8 * cK,
                  &sK[bi][(wave * 4 + j) * 512]);
            const int rV = ch >> 4, cV = (ch & 15) ^ (rV & 15);
            gld16(VTg + ((size_t)(bh * DK + rV)) * SEQ + k0 + 8 * cV,
                  &sV[bi][(wave * 4 + j) * 512]);
        }
    };

    stage(0, 0);
    #pragma unroll
    for (int i = 0; i < SEQ / (256 * 4); ++i) {
        const int idx = (i * 256 + t) * 4;
        const int4 mv = *reinterpret_cast<const int4*>(&mask[b * SEQ + idx]);
        madd[idx + 0] = (mv.x == 0) ? -1.442695e9f : 0.f;
        madd[idx + 1] = (mv.y == 0) ? -1.442695e9f : 0.f;
        madd[idx + 2] = (mv.z == 0) ? -1.442695e9f : 0.f;
        madd[idx + 3] = (mv.w == 0) ? -1.442695e9f : 0.f;
    }

    frag8 qf[2][2];
    #pragma unroll
    for (int s = 0; s < 2; ++s) {
        const bf16* qsrc = Qg + ((size_t)(b * SEQ + q0 + 32 * wave + 16 * s + lm)) * D_MODEL + h * DK;
        qf[s][0] = *reinterpret_cast<const frag8*>(qsrc + 8 * qd);
        qf[s][1] = *reinterpret_cast<const frag8*>(qsrc + 32 + 8 * qd);
    }

    facc4 accO[2][4];
    #pragma unroll
    for (int s = 0; s < 2; ++s)
        #pragma unroll
        for (int in = 0; in < 4; ++in) accO[s][in] = (facc4){0.f, 0.f, 0.f, 0.f};
    float m_r[2] = {-1e30f, -1e30f}, l_r[2] = {0.f, 0.f};

    for (int kt = 0; kt < SEQ / KTILE; ++kt) {
        const int cur = kt & 1;
        const int k0  = kt * KTILE;
        __syncthreads();
        if (kt + 1 < SEQ / KTILE) stage(cur ^ 1, kt + 1);

        facc4 accST[2][8];
        #pragma unroll
        for (int s = 0; s < 2; ++s)
            #pragma unroll
            for (int i = 0; i < 8; ++i) accST[s][i] = (facc4){0.f, 0.f, 0.f, 0.f};
        __builtin_amdgcn_s_setprio(1);
        #pragma unroll
        for (int i = 0; i < 8; ++i) {
            #pragma unroll
            for (int s2 = 0; s2 < 2; ++s2) {
                const int cr = 4 * s2 + qd;
                frag8 kf = *reinterpret_cast<const frag8*>(
                    &sK[cur][(16 * i + lm) * 64 + ((cr ^ (lm & 7)) << 3)]);
                accST[0][i] = __builtin_amdgcn_mfma_f32_16x16x32_bf16(kf, qf[0][s2], accST[0][i], 0, 0, 0);
                accST[1][i] = __builtin_amdgcn_mfma_f32_16x16x32_bf16(kf, qf[1][s2], accST[1][i], 0, 0, 0);
            }
        }
        __builtin_amdgcn_s_setprio(0);

        facc4 vmx[2];
        #pragma unroll
        for (int s = 0; s < 2; ++s) vmx[s] = (facc4){-1e30f, -1e30f, -1e30f, -1e30f};
        #pragma unroll
        for (int i = 0; i < 8; ++i) {
            const facc4 mv = *reinterpret_cast<const facc4*>(&madd[k0 + 16 * i + 4 * qd]);
            #pragma unroll
            for (int s = 0; s < 2; ++s) {
                #pragma unroll
                for (int r = 0; r < 4; ++r) {
                    accST[s][i][r] = fmaf(accST[s][i][r], SCL, mv[r]);
                    vmx[s][r] = fmaxf(vmx[s][r], accST[s][i][r]);
                }
            }
        }
        float mn[2], alpha[2] = {1.f, 1.f};
        bool resc[2];
        #pragma unroll
        for (int s = 0; s < 2; ++s) {
            const float mloc = fmaxf(fmaxf(vmx[s][0], vmx[s][1]), fmaxf(vmx[s][2], vmx[s][3]));
            const bool skip = __all(mloc - m_r[s] <= 11.54f) != 0;
            resc[s] = !skip;
            if (skip) {
                mn[s] = m_r[s];
            } else {
                float m0 = mloc;
                m0 = fmaxf(m0, __shfl_xor(m0, 16));
                m0 = fmaxf(m0, __shfl_xor(m0, 32));
                mn[s] = fmaxf(m_r[s], m0);
                alpha[s] = __builtin_amdgcn_exp2f(m_r[s] - mn[s]);
                m_r[s] = mn[s];
            }
        }

        unsigned up[2][8][2];
        facc4 ps4[2];
        #pragma unroll
        for (int s = 0; s < 2; ++s) ps4[s] = (facc4){0.f, 0.f, 0.f, 0.f};
        #pragma unroll
        for (int s = 0; s < 2; ++s) {
            #pragma unroll
            for (int i = 0; i < 8; ++i) {
                const float p0 = __builtin_amdgcn_exp2f(accST[s][i][0] - mn[s]);
                const float p1 = __builtin_amdgcn_exp2f(accST[s][i][1] - mn[s]);
                const float p2 = __builtin_amdgcn_exp2f(accST[s][i][2] - mn[s]);
                const float p3 = __builtin_amdgcn_exp2f(accST[s][i][3] - mn[s]);
                ps4[s][0] += p0; ps4[s][1] += p1; ps4[s][2] += p2; ps4[s][3] += p3;
                up[s][i][0] = cvtpk_bf16(p0, p1);
                up[s][i][1] = cvtpk_bf16(p2, p3);
            }
        }
        #pragma unroll
        for (int s = 0; s < 2; ++s) {
            float ps = (ps4[s][0] + ps4[s][1]) + (ps4[s][2] + ps4[s][3]);
            ps += __shfl_xor(ps, 16);
            ps += __shfl_xor(ps, 32);
            if (resc[s]) {
                l_r[s] = l_r[s] * alpha[s] + ps;
                #pragma unroll
                for (int in = 0; in < 4; ++in)
                    #pragma unroll
                    for (int r = 0; r < 4; ++r) accO[s][in][r] *= alpha[s];
            } else {
                l_r[s] += ps;
            }
        }

        __builtin_amdgcn_s_setprio(1);
        #pragma unroll
        for (int c = 0; c < 4; ++c) {
            union { frag8 f; unsigned u[4]; } pf0_, pf1_;
            #pragma unroll
            for (int s = 0; s < 2; ++s) {
                unsigned a0 = up[s][2*c][0],     a1 = up[s][2*c][1];
                unsigned b0 = up[s][2*c + 1][0], b1 = up[s][2*c + 1][1];
                asm("v_permlane32_swap_b32 %0, %1" : "+v"(a0), "+v"(b0));
                asm("v_permlane32_swap_b32 %0, %1" : "+v"(a1), "+v"(b1));
                const unsigned t0 = qo ? a0 : b0;
                const unsigned t1 = qo ? a1 : b1;
                const unsigned r0 = __shfl_xor(t0, 16);
                const unsigned r1 = __shfl_xor(t1, 16);
                unsigned u0 = qo ? r0 : a0;   // kk = 32c+8qd+0,1
                unsigned u1 = qo ? r1 : a1;   // kk = 32c+8qd+2,3
                unsigned u2 = qo ? b0 : r0;  // kk = 32c+8qd+4,5
                unsigned u3 = qo ? b1 : r1;  // kk = 32c+8qd+6,7
                if (s == 0) { pf0_.u[0]=u0; pf0_.u[1]=u1; pf0_.u[2]=u2; pf0_.u[3]=u3; }
                else        { pf1_.u[0]=u0; pf1_.u[1]=u1; pf1_.u[2]=u2; pf1_.u[3]=u3; }
            }
            #pragma unroll
            for (int in = 0; in < 4; ++in) {
                const int cr = 4 * c + qd;
                frag8 vf = *reinterpret_cast<const frag8*>(
                    &sV[cur][(16 * in + lm) * 128 + ((cr ^ lm) << 3)]);
                accO[0][in] = __builtin_amdgcn_mfma_f32_16x16x32_bf16(vf, pf0_.f, accO[0][in], 0, 0, 0);
                accO[1][in] = __builtin_amdgcn_mfma_f32_16x16x32_bf16(vf, pf1_.f, accO[1][in], 0, 0, 0);
            }
        }
        __builtin_amdgcn_s_setprio(0);
    }

    #pragma unroll
    for (int s = 0; s < 2; ++s) {
        const float invl = 1.f / l_r[s];
        bf16* crow = ctx + ((size_t)(b * SEQ + q0 + 32 * wave + 16 * s + lm)) * D_MODEL + h * DK;
        #pragma unroll
        for (int in = 0; in < 4; ++in) {
            union { uint2 v; unsigned u[2]; } ov;
            ov.u[0] = cvtpk_bf16(accO[s][in][0] * invl, accO[s][in][1] * invl);
            ov.u[1] = cvtpk_bf16(accO[s][in][2] * invl, accO[s][in][3] * invl);
            *reinterpret_cast<uint2*>(crow + 16 * in + 4 * qd) = ov.v;
        }
    }
}

// LayerNorm v3 (G13): 128 threads/row, row register-resident, wave shfl reduce
// + 2-entry LDS combine, cvt_pk packed stores. ddof=1.
template<bool BASE_WS, bool OUT_WS>
__global__ __launch_bounds__(128) void ln_kernel(const void* __restrict__ base,
    const bf16* __restrict__ addv, const bf16* __restrict__ addv2,
    const void* __restrict__ alpha, const void* __restrict__ bias,
    void* __restrict__ outp, const int* __restrict__ flagp)
{
    const bool inF32 = (*flagp) != 0;
    __shared__ float red[2];
    __shared__ float red2[2];
    const int row = blockIdx.x, t = threadIdx.x;
    const size_t off = (size_t)row * D_MODEL + t * 8;

    float v[8];
    {
        const U8 bz = ld8bf(base, off, BASE_WS ? false : inF32);
        uint4 a1 = *reinterpret_cast<const uint4*>(addv + off);
        const unsigned short* a1s = reinterpret_cast<const unsigned short*>(&a1);
        #pragma unroll
        for (int j = 0; j < 8; ++j) v[j] = bf2f(bz.v[j]) + bf2f(a1s[j]);
        if (addv2) {
            uint4 a2 = *reinterpret_cast<const uint4*>(addv2 + off);
            const unsigned short* a2s = reinterpret_cast<const unsigned short*>(&a2);
            #pragma unroll
            for (int j = 0; j < 8; ++j) v[j] += bf2f(a2s[j]);
        }
    }

    float s = ((v[0]+v[1]) + (v[2]+v[3])) + ((v[4]+v[5]) + (v[6]+v[7]));
    #pragma unroll
    for (int o = 1; o < 64; o <<= 1) s += __shfl_xor(s, o);
    if ((t & 63) == 0) red[t >> 6] = s;
    __syncthreads();
    const float mean = (red[0] + red[1]) * (1.f / (float)D_MODEL);

    float sq = 0.f;
    #pragma unroll
    for (int j = 0; j < 8; ++j) { const float d = v[j] - mean; sq += d * d; }
    #pragma unroll
    for (int o = 1; o < 64; o <<= 1) sq += __shfl_xor(sq, o);
    if ((t & 63) == 0) red2[t >> 6] = sq;
    __syncthreads();
    const float var = (red2[0] + red2[1]) * (1.f / (float)(D_MODEL - 1));
    const float inv = 1.f / (sqrtf(var) + LN_EPS);

    float av[8], bv[8];
    ld8f(alpha, t * 8, inF32, av);
    ld8f(bias,  t * 8, inF32, bv);
    float y[8];
    #pragma unroll
    for (int j = 0; j < 8; ++j)
        y[j] = av[j] * (v[j] - mean) * inv + bv[j];

    if (OUT_WS || !inF32) {
        union { uint4 u; unsigned w[4]; } o_;
        o_.w[0] = cvtpk_bf16(y[0], y[1]);
        o_.w[1] = cvtpk_bf16(y[2], y[3]);
        o_.w[2] = cvtpk_bf16(y[4], y[5]);
        o_.w[3] = cvtpk_bf16(y[6], y[7]);
        *reinterpret_cast<uint4*>((bf16*)outp + off) = o_.u;
    } else {
        float* op = (float*)outp + off;
        const float4 f0 = {y[0], y[1], y[2], y[3]};
        const float4 f1 = {y[4], y[5], y[6], y[7]};
        *reinterpret_cast<float4*>(op)     = f0;
        *reinterpret_cast<float4*>(op + 4) = f1;
    }
}

extern "C" void kernel_launch(void* const* d_in, const int* in_sizes, int n_in,
                              void* d_out, int out_size, void* d_ws, size_t ws_size,
                              hipStream_t stream)
{
    const void* x    = d_in[0];
    const int*  mask = (const int*)d_in[1];
    const void* wq   = d_in[2];
    const void* wk   = d_in[3];
    const void* wv   = d_in[4];
    const void* wo   = d_in[5];
    const void* wo_b = d_in[6];
    const void* w1   = d_in[7];
    const void* b1   = d_in[8];
    const void* w2   = d_in[9];
    const void* b2   = d_in[10];
    const void* al1  = d_in[11];
    const void* bi1  = d_in[12];
    const void* al2  = d_in[13];
    const void* bi2  = d_in[14];

    const size_t MB = 1024 * 1024;
    char* ws = (char*)d_ws;
    const bool BIG = ws_size >= 64 * MB + 4096;     // R8 confirmed this branch runs
    if (!BIG && ws_size < 56 * MB + 4096) return;   // loud fail: out stays 0

    if (BIG) {
        // 64 MB plan. QKV (gemm256 NMAT=3) writes Q[0,8) K[8,16) V^T [16,24).
        bf16* Qb   = (bf16*)(ws + 0 * MB);
        bf16* Kb   = (bf16*)(ws + 8 * MB);
        bf16* VTb  = (bf16*)(ws + 16 * MB);
        bf16* Xb   = (bf16*)(ws + 24 * MB);
        bf16* WT4  = (bf16*)(ws + 32 * MB);
        bf16* WOT  = WT4 + (size_t)3 * D_MODEL * D_MODEL;
        bf16* W1T  = (bf16*)(ws + 40 * MB);
        bf16* W2T  = (bf16*)(ws + 48 * MB);
        bf16* CTXb = (bf16*)(ws + 56 * MB);
        bf16* ATT0 = (bf16*)(ws + 0 * MB);
        bf16* ATT1 = (bf16*)(ws + 8 * MB);
        bf16* X1b  = (bf16*)(ws + 56 * MB);
        bf16* FFb  = (bf16*)(ws + 0 * MB);
        bf16* X20  = (bf16*)(ws + 32 * MB);
        bf16* X21  = (bf16*)(ws + 40 * MB);
        int*  flagp = (int*)(ws + 64 * MB);

        probe_kernel<<<1, 256, 0, stream>>>(x, flagp);
        prep_kernel<<<dim3(5120), 256, 0, stream>>>(x, Xb, wq, wk, wv, wo, WT4,
                                                    w1, w2, W1T, W2T, flagp);

        gemm256_kernel<false, false, 3><<<dim3(12, 16), 512, 0, stream>>>(
            Xb, WT4, nullptr, Qb, ROWS, D_MODEL, D_MODEL, flagp);

        fattn_kernel<<<dim3(SEQ / 128, N_HEADS, BATCH), 256, 0, stream>>>(Qb, Kb, VTb, mask, CTXb);

        mgemm_kernel<false, true, 1, 2><<<dim3(8, 32, 2), 256, 0, stream>>>(
            CTXb, WOT, wo_b, ATT0, ROWS, D_MODEL, D_MODEL, flagp);
        ln_kernel<false, true><<<ROWS, 128, 0, stream>>>(x, ATT0, ATT1, al1, bi1, X1b, flagp);

        gemm256_kernel<true, true, 1><<<dim3(16, 16), 512, 0, stream>>>(
            X1b, W1T, b1, FFb, ROWS, D_FF, D_MODEL, flagp);

        mgemm_kernel<false, true, 1, 2><<<dim3(8, 32, 2), 256, 0, stream>>>(
            FFb, W2T, b2, X20, ROWS, D_MODEL, D_FF, flagp);
        ln_kernel<true, false><<<ROWS, 128, 0, stream>>>(X1b, X20, X21, al2, bi2, d_out, flagp);
    } else {
        // 56 MB fallback (no split-K). QKV (gemm256 NMAT=3) writes V^T into [16,24).
        bf16* Qb    = (bf16*)(ws + 0 * MB);
        bf16* Kb    = (bf16*)(ws + 8 * MB);
        bf16* VTb   = (bf16*)(ws + 16 * MB);
        bf16* Xb    = (bf16*)(ws + 24 * MB);
        bf16* WQKVT = (bf16*)(ws + 32 * MB);
        bf16* CTXb  = (bf16*)(ws + 32 * MB);
        bf16* W2T   = (bf16*)(ws + 32 * MB);
        bf16* WOT   = (bf16*)(ws + 0 * MB);
        bf16* ATT0  = (bf16*)(ws + 48 * MB);
        bf16* W1T   = (bf16*)(ws + 48 * MB);
        bf16* X20   = (bf16*)(ws + 48 * MB);
        bf16* X1b   = (bf16*)(ws + 40 * MB);
        bf16* FFb   = (bf16*)(ws + 0 * MB);
        int*  flagp = (int*)(ws + 56 * MB);

        probe_kernel<<<1, 256, 0, stream>>>(x, flagp);
        xcvt_kernel<<<dim3(ROWS * D_MODEL / 2048), 256, 0, stream>>>(x, Xb, flagp);

        transpose_kernel<<<dim3(16, 16), 256, 0, stream>>>(wq, WQKVT,           D_MODEL, D_MODEL, flagp);
        transpose_kernel<<<dim3(16, 16), 256, 0, stream>>>(wk, WQKVT + 1048576, D_MODEL, D_MODEL, flagp);
        transpose_kernel<<<dim3(16, 16), 256, 0, stream>>>(wv, WQKVT + 2097152, D_MODEL, D_MODEL, flagp);

        gemm256_kernel<false, false, 3><<<dim3(12, 16), 512, 0, stream>>>(
            Xb, WQKVT, nullptr, Qb, ROWS, D_MODEL, D_MODEL, flagp);

        fattn_kernel<<<dim3(SEQ / 128, N_HEADS, BATCH), 256, 0, stream>>>(Qb, Kb, VTb, mask, CTXb);

        transpose_kernel<<<dim3(16, 16), 256, 0, stream>>>(wo, WOT, D_MODEL, D_MODEL, flagp);
        mgemm_kernel<false, true, 1, 1><<<dim3(8, 32), 256, 0, stream>>>(
            CTXb, WOT, wo_b, ATT0, ROWS, D_MODEL, D_MODEL, flagp);
        ln_kernel<false, true><<<ROWS, 128, 0, stream>>>(x, ATT0, nullptr, al1, bi1, X1b, flagp);

        transpose_kernel<<<dim3(64, 16), 256, 0, stream>>>(w1, W1T, D_MODEL, D_FF, flagp);
        gemm256_kernel<true, true, 1><<<dim3(16, 16), 512, 0, stream>>>(
            X1b, W1T, b1, FFb, ROWS, D_FF, D_MODEL, flagp);

        transpose_kernel<<<dim3(16, 64), 256, 0, stream>>>(w2, W2T, D_FF, D_MODEL, flagp);
        mgemm_kernel<false, true, 1, 1><<<dim3(8, 32), 256, 0, stream>>>(
            FFb, W2T, b2, X20, ROWS, D_MODEL, D_FF, flagp);
        ln_kernel<true, false><<<ROWS, 128, 0, stream>>>(X1b, X20, nullptr, al2, bi2, d_out, flagp);
    }
}